// Round 1
// baseline (580.470 us; speedup 1.0000x reference)
//
#include <hip/hip_runtime.h>
#include <hip/hip_bf16.h>

// HiMambaBottleneck: B=8, C=384, H=W=32, L=1024, BL=8192, dt_rank=24, N=16.
// Strategy:
//  - in_proj GEMM computed ONCE (pointwise => shared by fwd/bwd).
//  - out_proj GEMM computed ONCE on (S_fwd + flip(S_bwd)) (linearity).
//  - selective scan fused: exp/deltaA/deltaBu computed inline, LDS-chunked
//    double-buffered input staging, shfl_xor reduce over 16 states.
//  - GEMMs in bf16 MFMA 16x16x32, f32 accumulate; padded weights so no guards.

typedef __attribute__((ext_vector_type(8))) short bf16x8;
typedef __attribute__((ext_vector_type(4))) float f32x4;

#define L2E 1.44269504088896340736f

static __device__ __forceinline__ unsigned short f2bf(float f) {
  unsigned int u = __builtin_bit_cast(unsigned int, f);
  u += 0x7fff + ((u >> 16) & 1);  // RNE
  return (unsigned short)(u >> 16);
}

// ---------------- prep: weights -> bf16 (padded), A2 table ----------------
__global__ __launch_bounds__(256) void prep_k(
    const float* __restrict__ in_w, const float* __restrict__ x_w,
    const float* __restrict__ dt_w, const float* __restrict__ out_w,
    const float* __restrict__ A_log,
    unsigned short* __restrict__ W_in, unsigned short* __restrict__ W_x,
    unsigned short* __restrict__ W_dt, unsigned short* __restrict__ W_out,
    float* __restrict__ A2) {
  int idx = blockIdx.x * 256 + threadIdx.x;
  switch (blockIdx.y) {
    case 0: if (idx < 768 * 384) W_in[idx] = f2bf(in_w[idx]); break;
    case 1: if (idx < 64 * 384) { int n = idx / 384, k = idx - n * 384;
              W_x[idx] = f2bf(n < 56 ? x_w[n * 384 + k] : 0.f); } break;
    case 2: if (idx < 384 * 32) { int n = idx >> 5, k = idx & 31;
              W_dt[idx] = f2bf(k < 24 ? dt_w[n * 24 + k] : 0.f); } break;
    case 3: if (idx < 384 * 384) W_out[idx] = f2bf(out_w[idx]); break;
    case 4: if (idx < 384 * 16) A2[idx] = -expf(A_log[idx]) * L2E; break;
  }
}

// ---------------- rmsnorm: x NCHW -> xn channels-last (f32 + bf16) --------
__global__ __launch_bounds__(384) void rmsnorm_k(
    const float* __restrict__ x, const float* __restrict__ nw,
    float* __restrict__ xn, unsigned short* __restrict__ xnb) {
  const int bl = blockIdx.x;            // b*1024 + l
  const int b = bl >> 10, l = bl & 1023;
  const int c = threadIdx.x;
  float v = x[((size_t)(b * 384 + c) << 10) + l];
  float sq = v * v;
  #pragma unroll
  for (int m = 1; m < 64; m <<= 1) sq += __shfl_xor(sq, m);
  __shared__ float ws[6];
  if ((threadIdx.x & 63) == 0) ws[threadIdx.x >> 6] = sq;
  __syncthreads();
  float ssq = ws[0] + ws[1] + ws[2] + ws[3] + ws[4] + ws[5];
  float o = v * rsqrtf(ssq * (1.f / 384.f) + 1e-6f) * nw[c];
  size_t oi = (size_t)bl * 384 + c;
  xn[oi] = o;
  xnb[oi] = f2bf(o);
}

// ---------------- generic bf16 MFMA GEMM: C[M,N] = A[M,K] * W[N,K]^T ------
// 64x64 tile, 4 waves (2x2), BK=32. M,N,K multiples of 64/64/32 (padded).
template <int EPI>
__global__ __launch_bounds__(256) void gemm_k(
    const unsigned short* __restrict__ A, const unsigned short* __restrict__ Bw,
    int K, int N,
    float* __restrict__ out0, unsigned short* __restrict__ outb,
    const float* __restrict__ bias, const float* __restrict__ scale) {
  __shared__ unsigned short As[64][40];  // +8 pad: 2-way LDS conflict (free)
  __shared__ unsigned short Bs[64][40];
  const int m0 = blockIdx.x * 64, n0 = blockIdx.y * 64;
  const int tid = threadIdx.x;
  const int lane = tid & 63, wave = tid >> 6;
  const int wm = wave >> 1, wn = wave & 1;
  const int lrow = tid >> 2, lseg = (tid & 3) * 8;
  const int fr = lane & 15, ks = (lane >> 4) * 8;
  f32x4 acc[2][2] = {};
  for (int k0 = 0; k0 < K; k0 += 32) {
    __syncthreads();
    *(bf16x8*)&As[lrow][lseg] = *(const bf16x8*)&A[(size_t)(m0 + lrow) * K + k0 + lseg];
    *(bf16x8*)&Bs[lrow][lseg] = *(const bf16x8*)&Bw[(size_t)(n0 + lrow) * K + k0 + lseg];
    __syncthreads();
    bf16x8 a0 = *(const bf16x8*)&As[wm * 32 + fr][ks];
    bf16x8 a1 = *(const bf16x8*)&As[wm * 32 + 16 + fr][ks];
    bf16x8 b0 = *(const bf16x8*)&Bs[wn * 32 + fr][ks];
    bf16x8 b1 = *(const bf16x8*)&Bs[wn * 32 + 16 + fr][ks];
    acc[0][0] = __builtin_amdgcn_mfma_f32_16x16x32_bf16(a0, b0, acc[0][0], 0, 0, 0);
    acc[0][1] = __builtin_amdgcn_mfma_f32_16x16x32_bf16(a0, b1, acc[0][1], 0, 0, 0);
    acc[1][0] = __builtin_amdgcn_mfma_f32_16x16x32_bf16(a1, b0, acc[1][0], 0, 0, 0);
    acc[1][1] = __builtin_amdgcn_mfma_f32_16x16x32_bf16(a1, b1, acc[1][1], 0, 0, 0);
  }
  #pragma unroll
  for (int mi = 0; mi < 2; ++mi)
    #pragma unroll
    for (int ni = 0; ni < 2; ++ni)
      #pragma unroll
      for (int j = 0; j < 4; ++j) {
        int m = m0 + wm * 32 + mi * 16 + (lane >> 4) * 4 + j;
        int n = n0 + wn * 32 + ni * 16 + (lane & 15);
        float v = acc[mi][ni][j];
        if (EPI == 0) {                       // plain f32 (in_proj -> xz)
          out0[(size_t)m * N + n] = v;
        } else if (EPI == 1) {                // x_proj split: dt->bf16 pad, B/C->f32
          if (n < 24) outb[m * 32 + n] = f2bf(v);
          else if (n < 32) outb[m * 32 + n] = 0;  // bf16 zero
          if (n >= 24 && n < 56) out0[m * 32 + (n - 24)] = v;
        } else if (EPI == 2) {                // dt_proj: +bias, softplus -> delta
          float t = v + bias[n];
          out0[(size_t)m * N + n] = (t > 20.f) ? t : log1pf(expf(t));
        } else {                              // out_proj: * scale_mod -> G
          out0[(size_t)m * N + n] = v * scale[0];
        }
      }
}

// ---------------- causal depthwise conv1d + silu (both directions) --------
__global__ __launch_bounds__(384) void conv_silu_k(
    const float* __restrict__ xz, const float* __restrict__ cw,
    const float* __restrict__ cb,
    float* __restrict__ u0, float* __restrict__ u1,
    unsigned short* __restrict__ ub0, unsigned short* __restrict__ ub1) {
  const int s = blockIdx.x, b = blockIdx.y, dir = blockIdx.z;
  const int c = threadIdx.x;
  float acc = cb[c];
  #pragma unroll
  for (int k = 0; k < 4; ++k) {
    int j = s - 3 + k;
    if (j >= 0) {
      int t = dir ? (1023 - j) : j;
      acc += xz[(size_t)((b << 10) + t) * 768 + c] * cw[c * 4 + k];
    }
  }
  float uv = acc / (1.f + expf(-acc));  // silu
  size_t o = (size_t)((b << 10) + s) * 384 + c;
  if (dir == 0) { u0[o] = uv; ub0[o] = f2bf(uv); }
  else          { u1[o] = uv; ub1[o] = f2bf(uv); }
}

// ---------------- selective scan (fused dA/dBu/y/silu(z)/u*D) -------------
// lane = (c_sub[4] x n[16]); block = 16 channels; chunked LDS double-buffer.
__global__ __launch_bounds__(256) void scan_k(
    const float* __restrict__ d0, const float* __restrict__ d1,
    const float* __restrict__ u0, const float* __restrict__ u1,
    const float* __restrict__ bc0, const float* __restrict__ bc1,
    const float* __restrict__ xz, const float* __restrict__ A2,
    const float* __restrict__ Dp,
    float* __restrict__ S0, float* __restrict__ S1) {
  const int ct = blockIdx.x, b = blockIdx.y, dir = blockIdx.z;
  const float* del = dir ? d1 : d0;
  const float* uu  = dir ? u1 : u0;
  const float* bc  = dir ? bc1 : bc0;
  float* S = dir ? S1 : S0;
  const int tid = threadIdx.x;
  const int lane = tid & 63, wave = tid >> 6;
  const int n = lane & 15, cg = lane >> 4;
  const int cl = wave * 4 + cg;       // local channel 0..15
  const int c = ct * 16 + cl;
  const float a2 = A2[c * 16 + n];
  const float dpc = Dp[c];
  __shared__ float sd[2][16][16], su[2][16][16], sz[2][16][16], sbc[2][16][32];
  const int li = tid >> 4, lj = tid & 15;
  const int bi = tid >> 5, bj = tid & 31;
  float h = 0.f;
  float rd, ru, rz, rb0, rb1;
  auto issue = [&](int s0) {
    size_t row = (size_t)((b << 10) + s0 + li);
    rd = del[row * 384 + ct * 16 + lj];
    ru = uu[row * 384 + ct * 16 + lj];
    int t = dir ? (1023 - (s0 + li)) : (s0 + li);
    rz = xz[(size_t)((b << 10) + t) * 768 + 384 + ct * 16 + lj];
    rb0 = bc[(size_t)((b << 10) + s0 + bi) * 32 + bj];
    rb1 = bc[(size_t)((b << 10) + s0 + bi + 8) * 32 + bj];
  };
  auto commit = [&](int buf) {
    sd[buf][li][lj] = rd; su[buf][li][lj] = ru; sz[buf][li][lj] = rz;
    sbc[buf][bi][bj] = rb0; sbc[buf][bi + 8][bj] = rb1;
  };
  issue(0); commit(0);
  for (int ch = 0; ch < 64; ++ch) {
    const int cur = ch & 1;
    if (ch + 1 < 64) issue((ch + 1) * 16);   // loads in flight over compute
    __syncthreads();                          // LDS[cur] ready
    #pragma unroll
    for (int i = 0; i < 16; ++i) {
      float dlt = sd[cur][i][cl];
      float uv  = su[cur][i][cl];
      float bm = sbc[cur][i][n];
      float cm = sbc[cur][i][16 + n];
      float dA = exp2f(dlt * a2);            // exp(delta*A), A2 = A*log2e
      h = fmaf(dA, h, dlt * uv * bm);
      float p = h * cm;
      p += __shfl_xor(p, 1); p += __shfl_xor(p, 2);
      p += __shfl_xor(p, 4); p += __shfl_xor(p, 8);
      if (n == 0) {
        float zz = sz[cur][i][cl];
        float y = (p + uv * dpc) * (zz / (1.f + expf(-zz)));
        int s = ch * 16 + i;
        int t = dir ? (1023 - s) : s;
        S[(size_t)((b << 10) + t) * 384 + c] = y;
      }
    }
    if (ch + 1 < 64) commit(cur ^ 1);
  }
}

// ---------------- Ssum = bf16(S0 + S1) ------------------------------------
__global__ __launch_bounds__(256) void ssum_k(
    const float* __restrict__ S0, const float* __restrict__ S1,
    unsigned short* __restrict__ Sb) {
  int i = blockIdx.x * 256 + threadIdx.x;     // *4 floats
  float4 a = ((const float4*)S0)[i];
  float4 b = ((const float4*)S1)[i];
  ushort4 r;
  r.x = f2bf(a.x + b.x); r.y = f2bf(a.y + b.y);
  r.z = f2bf(a.z + b.z); r.w = f2bf(a.w + b.w);
  ((ushort4*)Sb)[i] = r;
}

// ---------------- final: dwconv3x3 gate + transpose + residual ------------
__global__ __launch_bounds__(256) void final_k(
    const float* __restrict__ G, const float* __restrict__ xn,
    const float* __restrict__ x, const float* __restrict__ dww,
    const float* __restrict__ dwb, const float* __restrict__ rs,
    float* __restrict__ out) {
  __shared__ float tile[64][33];
  const int l0 = blockIdx.x * 32, c0 = blockIdx.y * 64, b = blockIdx.z;
  const int tid = threadIdx.x;
  {
    const int cj = tid & 63, li = tid >> 6;   // c-coalesced phase
    const int c = c0 + cj;
    float w[9];
    #pragma unroll
    for (int q = 0; q < 9; ++q) w[q] = dww[c * 9 + q];
    const float bb = dwb[c];
    for (int p = 0; p < 8; ++p) {
      int l = l0 + p * 4 + li;
      int hh = l >> 5, ww = l & 31;
      float acc = bb;
      #pragma unroll
      for (int di = -1; di <= 1; ++di) {
        int h2 = hh + di; if (h2 < 0 || h2 > 31) continue;
        #pragma unroll
        for (int dj = -1; dj <= 1; ++dj) {
          int w2 = ww + dj; if (w2 < 0 || w2 > 31) continue;
          acc += xn[(size_t)((b << 10) + h2 * 32 + w2) * 384 + c] * w[(di + 1) * 3 + dj + 1];
        }
      }
      size_t ri = (size_t)((b << 10) + l) * 384 + c;
      float xv = xn[ri];
      float F = G[ri] + xv / (1.f + expf(-acc));  // global + sigmoid(conv)*xn
      tile[cj][p * 4 + li] = F;
    }
  }
  __syncthreads();
  {
    const int lw = tid & 31, cr = tid >> 5;   // l-coalesced phase
    const float rsv = rs[0];
    for (int p = 0; p < 8; ++p) {
      int c = c0 + p * 8 + cr;
      size_t o = ((size_t)(b * 384 + c) << 10) + l0 + lw;
      out[o] = x[o] + rsv * tile[p * 8 + cr][lw];
    }
  }
}

// ---------------- host ----------------------------------------------------
extern "C" void kernel_launch(void* const* d_in, const int* in_sizes, int n_in,
                              void* d_out, int out_size, void* d_ws, size_t ws_size,
                              hipStream_t stream) {
  const float* x         = (const float*)d_in[0];
  const float* norm_w    = (const float*)d_in[1];
  const float* in_proj_w = (const float*)d_in[2];
  const float* conv1d_w  = (const float*)d_in[3];
  const float* conv1d_b  = (const float*)d_in[4];
  const float* x_proj_w  = (const float*)d_in[5];
  const float* dt_proj_w = (const float*)d_in[6];
  const float* dt_proj_b = (const float*)d_in[7];
  const float* A_log     = (const float*)d_in[8];
  const float* D_param   = (const float*)d_in[9];
  const float* out_proj_w= (const float*)d_in[10];
  const float* scale_mod = (const float*)d_in[11];
  const float* dw_w      = (const float*)d_in[12];
  const float* dw_b      = (const float*)d_in[13];
  const float* res_scale = (const float*)d_in[14];
  float* out = (float*)d_out;

  char* base = (char*)d_ws;
  size_t off = 0;
  auto alloc = [&](size_t bytes) {
    off = (off + 255) & ~(size_t)255;
    void* p = base + off;
    off += bytes;
    return p;
  };
  const size_t F_BLC  = (size_t)8192 * 384 * 4;   // 12.58 MB
  const size_t B_BLC  = (size_t)8192 * 384 * 2;   // 6.29 MB

  float*          xn_f = (float*)alloc(F_BLC);
  unsigned short* xn_b = (unsigned short*)alloc(B_BLC);
  float*          xz   = (float*)alloc((size_t)8192 * 768 * 4);
  float*          u_f0 = (float*)alloc(F_BLC);
  float*          u_f1 = (float*)alloc(F_BLC);
  unsigned short* u_b0 = (unsigned short*)alloc(B_BLC);
  unsigned short* u_b1 = (unsigned short*)alloc(B_BLC);
  unsigned short* dtp0 = (unsigned short*)alloc((size_t)8192 * 32 * 2);
  unsigned short* dtp1 = (unsigned short*)alloc((size_t)8192 * 32 * 2);
  float*          bc0  = (float*)alloc((size_t)8192 * 32 * 4);
  float*          bc1  = (float*)alloc((size_t)8192 * 32 * 4);
  float*          de0  = (float*)alloc(F_BLC);
  float*          de1  = (float*)alloc(F_BLC);
  float*          S0   = (float*)alloc(F_BLC);
  float*          S1   = (float*)alloc(F_BLC);
  unsigned short* W_in = (unsigned short*)alloc((size_t)768 * 384 * 2);
  unsigned short* W_x  = (unsigned short*)alloc((size_t)64 * 384 * 2);
  unsigned short* W_dt = (unsigned short*)alloc((size_t)384 * 32 * 2);
  unsigned short* W_out= (unsigned short*)alloc((size_t)384 * 384 * 2);
  float*          A2   = (float*)alloc((size_t)384 * 16 * 4);
  // reuse (lifetimes disjoint in stream order):
  unsigned short* Ssum = (unsigned short*)de0;   // after scan, before out_proj
  float*          G    = xz;                     // after scan (z consumed)

  prep_k<<<dim3(1152, 5), 256, 0, stream>>>(in_proj_w, x_proj_w, dt_proj_w,
                                            out_proj_w, A_log,
                                            W_in, W_x, W_dt, W_out, A2);
  rmsnorm_k<<<8192, 384, 0, stream>>>(x, norm_w, xn_f, xn_b);
  gemm_k<0><<<dim3(128, 12), 256, 0, stream>>>(xn_b, W_in, 384, 768, xz,
                                               nullptr, nullptr, nullptr);
  conv_silu_k<<<dim3(1024, 8, 2), 384, 0, stream>>>(xz, conv1d_w, conv1d_b,
                                                    u_f0, u_f1, u_b0, u_b1);
  gemm_k<1><<<dim3(128, 1), 256, 0, stream>>>(u_b0, W_x, 384, 64, bc0, dtp0,
                                              nullptr, nullptr);
  gemm_k<1><<<dim3(128, 1), 256, 0, stream>>>(u_b1, W_x, 384, 64, bc1, dtp1,
                                              nullptr, nullptr);
  gemm_k<2><<<dim3(128, 6), 256, 0, stream>>>(dtp0, W_dt, 32, 384, de0,
                                              nullptr, dt_proj_b, nullptr);
  gemm_k<2><<<dim3(128, 6), 256, 0, stream>>>(dtp1, W_dt, 32, 384, de1,
                                              nullptr, dt_proj_b, nullptr);
  scan_k<<<dim3(24, 8, 2), 256, 0, stream>>>(de0, de1, u_f0, u_f1, bc0, bc1,
                                             xz, A2, D_param, S0, S1);
  ssum_k<<<3072, 256, 0, stream>>>(S0, S1, Ssum);
  gemm_k<3><<<dim3(128, 6), 256, 0, stream>>>(Ssum, W_out, 384, 384, G,
                                              nullptr, nullptr, scale_mod);
  final_k<<<dim3(32, 6, 8), 256, 0, stream>>>(G, xn_f, x, dw_w, dw_b,
                                              res_scale, out);
}

// Round 2
// 289.358 us; speedup vs baseline: 2.0061x; 2.0061x over previous
//
#include <hip/hip_runtime.h>
#include <hip/hip_bf16.h>

// HiMambaBottleneck: B=8, C=384, H=W=32, L=1024, BL=8192, dt_rank=24, N=16.
//  - in_proj GEMM computed ONCE (pointwise => shared by fwd/bwd).
//  - out_proj GEMM computed ONCE on (S_fwd + flip(S_bwd)) (linearity).
//  - scan: chunk-of-16 batched compute; 16-FMA serial core; butterfly reduce.

typedef __attribute__((ext_vector_type(8))) short bf16x8;
typedef __attribute__((ext_vector_type(4))) float f32x4;

#define L2E 1.44269504088896340736f

static __device__ __forceinline__ unsigned short f2bf(float f) {
  unsigned int u = __builtin_bit_cast(unsigned int, f);
  u += 0x7fff + ((u >> 16) & 1);  // RNE
  return (unsigned short)(u >> 16);
}

// ---------------- prep: weights -> bf16 (padded), A2 table ----------------
__global__ __launch_bounds__(256) void prep_k(
    const float* __restrict__ in_w, const float* __restrict__ x_w,
    const float* __restrict__ dt_w, const float* __restrict__ out_w,
    const float* __restrict__ A_log,
    unsigned short* __restrict__ W_in, unsigned short* __restrict__ W_x,
    unsigned short* __restrict__ W_dt, unsigned short* __restrict__ W_out,
    float* __restrict__ A2) {
  int idx = blockIdx.x * 256 + threadIdx.x;
  switch (blockIdx.y) {
    case 0: if (idx < 768 * 384) W_in[idx] = f2bf(in_w[idx]); break;
    case 1: if (idx < 64 * 384) { int n = idx / 384, k = idx - n * 384;
              W_x[idx] = f2bf(n < 56 ? x_w[n * 384 + k] : 0.f); } break;
    case 2: if (idx < 384 * 32) { int n = idx >> 5, k = idx & 31;
              W_dt[idx] = f2bf(k < 24 ? dt_w[n * 24 + k] : 0.f); } break;
    case 3: if (idx < 384 * 384) W_out[idx] = f2bf(out_w[idx]); break;
    case 4: if (idx < 384 * 16) A2[idx] = -expf(A_log[idx]) * L2E; break;
  }
}

// ---------------- rmsnorm: x NCHW -> xn channels-last (f32 + bf16) --------
// block = (b, 32-l tile); l-coalesced reads, LDS transpose for c-coalesced
// writes. Second read of x hits L2.
__global__ __launch_bounds__(256) void rmsnorm_k(
    const float* __restrict__ x, const float* __restrict__ nw,
    float* __restrict__ xn, unsigned short* __restrict__ xnb) {
  const int b = blockIdx.y;
  const int l0 = blockIdx.x * 32;
  const int tid = threadIdx.x;
  const int ci = tid >> 5, lw = tid & 31;
  __shared__ float part[8][33];
  __shared__ float nf[32];
  __shared__ float t64[64][33];
  float acc = 0.f;
  for (int cc = ci; cc < 384; cc += 8) {
    float v = x[(((size_t)(b * 384 + cc)) << 10) + l0 + lw];
    acc = fmaf(v, v, acc);
  }
  part[ci][lw] = acc;
  __syncthreads();
  if (tid < 32) {
    float s = part[0][tid] + part[1][tid] + part[2][tid] + part[3][tid] +
              part[4][tid] + part[5][tid] + part[6][tid] + part[7][tid];
    nf[tid] = rsqrtf(s * (1.f / 384.f) + 1e-6f);
  }
  __syncthreads();
  const int cr = tid >> 5;          // phase-2 read mapping
  const int cj = tid & 63, lr = tid >> 6;  // phase-2 write mapping
  for (int cc = 0; cc < 6; ++cc) {
    #pragma unroll
    for (int k = 0; k < 8; ++k) {
      int cp = cr + k * 8;
      int c = cc * 64 + cp;
      float v = x[(((size_t)(b * 384 + c)) << 10) + l0 + lw];
      t64[cp][lw] = v * nf[lw] * nw[c];
    }
    __syncthreads();
    #pragma unroll
    for (int k2 = 0; k2 < 8; ++k2) {
      int ll = lr + 4 * k2;
      float val = t64[cj][ll];
      size_t a = ((size_t)((b << 10) + l0 + ll)) * 384 + cc * 64 + cj;
      xn[a] = val;
      xnb[a] = f2bf(val);
    }
    __syncthreads();
  }
}

// ---------------- generic bf16 MFMA GEMM: C[M,N] = A[M,K] * W[N,K]^T ------
template <int EPI>
__global__ __launch_bounds__(256) void gemm_k(
    const unsigned short* __restrict__ A, const unsigned short* __restrict__ Bw,
    int K, int N,
    float* __restrict__ out0, unsigned short* __restrict__ outb,
    const float* __restrict__ bias, const float* __restrict__ scale) {
  __shared__ unsigned short As[64][40];
  __shared__ unsigned short Bs[64][40];
  const int m0 = blockIdx.x * 64, n0 = blockIdx.y * 64;
  const int tid = threadIdx.x;
  const int lane = tid & 63, wave = tid >> 6;
  const int wm = wave >> 1, wn = wave & 1;
  const int lrow = tid >> 2, lseg = (tid & 3) * 8;
  const int fr = lane & 15, ks = (lane >> 4) * 8;
  f32x4 acc[2][2] = {};
  for (int k0 = 0; k0 < K; k0 += 32) {
    __syncthreads();
    *(bf16x8*)&As[lrow][lseg] = *(const bf16x8*)&A[(size_t)(m0 + lrow) * K + k0 + lseg];
    *(bf16x8*)&Bs[lrow][lseg] = *(const bf16x8*)&Bw[(size_t)(n0 + lrow) * K + k0 + lseg];
    __syncthreads();
    bf16x8 a0 = *(const bf16x8*)&As[wm * 32 + fr][ks];
    bf16x8 a1 = *(const bf16x8*)&As[wm * 32 + 16 + fr][ks];
    bf16x8 b0 = *(const bf16x8*)&Bs[wn * 32 + fr][ks];
    bf16x8 b1 = *(const bf16x8*)&Bs[wn * 32 + 16 + fr][ks];
    acc[0][0] = __builtin_amdgcn_mfma_f32_16x16x32_bf16(a0, b0, acc[0][0], 0, 0, 0);
    acc[0][1] = __builtin_amdgcn_mfma_f32_16x16x32_bf16(a0, b1, acc[0][1], 0, 0, 0);
    acc[1][0] = __builtin_amdgcn_mfma_f32_16x16x32_bf16(a1, b0, acc[1][0], 0, 0, 0);
    acc[1][1] = __builtin_amdgcn_mfma_f32_16x16x32_bf16(a1, b1, acc[1][1], 0, 0, 0);
  }
  #pragma unroll
  for (int mi = 0; mi < 2; ++mi)
    #pragma unroll
    for (int ni = 0; ni < 2; ++ni)
      #pragma unroll
      for (int j = 0; j < 4; ++j) {
        int m = m0 + wm * 32 + mi * 16 + (lane >> 4) * 4 + j;
        int n = n0 + wn * 32 + ni * 16 + (lane & 15);
        float v = acc[mi][ni][j];
        if (EPI == 0) {
          out0[(size_t)m * N + n] = v;
        } else if (EPI == 1) {
          if (n < 24) outb[m * 32 + n] = f2bf(v);
          else if (n < 32) outb[m * 32 + n] = 0;
          if (n >= 24 && n < 56) out0[m * 32 + (n - 24)] = v;
        } else if (EPI == 2) {
          float t = v + bias[n];
          out0[(size_t)m * N + n] = (t > 20.f) ? t : log1pf(expf(t));
        } else {
          out0[(size_t)m * N + n] = v * scale[0];
        }
      }
}

// ---------------- causal depthwise conv1d + silu (both directions) --------
// block computes 8 timesteps from an 11-tap register window.
__global__ __launch_bounds__(384) void conv_silu_k(
    const float* __restrict__ xz, const float* __restrict__ cw,
    const float* __restrict__ cb,
    float* __restrict__ u0, float* __restrict__ u1,
    unsigned short* __restrict__ ub0, unsigned short* __restrict__ ub1) {
  const int st = blockIdx.x, b = blockIdx.y, dir = blockIdx.z;
  const int c = threadIdx.x;
  const int s0 = st * 8;
  const float w0 = cw[c * 4 + 0], w1 = cw[c * 4 + 1];
  const float w2 = cw[c * 4 + 2], w3 = cw[c * 4 + 3];
  const float bb = cb[c];
  float* uf = dir ? u1 : u0;
  unsigned short* ub = dir ? ub1 : ub0;
  float xv[11];
  #pragma unroll
  for (int k = 0; k < 11; ++k) {
    int j = s0 - 3 + k;
    float v = 0.f;
    if (j >= 0) {
      int t = dir ? (1023 - j) : j;
      v = xz[(size_t)((b << 10) + t) * 768 + c];
    }
    xv[k] = v;
  }
  #pragma unroll
  for (int s = 0; s < 8; ++s) {
    float a = bb + xv[s] * w0 + xv[s + 1] * w1 + xv[s + 2] * w2 + xv[s + 3] * w3;
    float uv = a * __builtin_amdgcn_rcpf(1.f + __builtin_amdgcn_exp2f(-a * L2E));
    size_t o = (size_t)((b << 10) + s0 + s) * 384 + c;
    uf[o] = uv;
    ub[o] = f2bf(uv);
  }
}

// ---------------- selective scan, chunk-batched ---------------------------
// wave = 4 channels x 16 states; chunk = 16 steps; LDS transposed [c][t];
// serial core = 16 chained FMAs; distributed butterfly reduce over n.
__global__ __launch_bounds__(256) void scan_k(
    const float* __restrict__ d0, const float* __restrict__ d1,
    const float* __restrict__ u0, const float* __restrict__ u1,
    const float* __restrict__ bc0, const float* __restrict__ bc1,
    const float* __restrict__ xz, const float* __restrict__ A2,
    const float* __restrict__ Dp,
    float* __restrict__ S0, float* __restrict__ S1) {
  const int ct = blockIdx.x, b = blockIdx.y, dir = blockIdx.z;
  const float* del = dir ? d1 : d0;
  const float* uu  = dir ? u1 : u0;
  const float* bc  = dir ? bc1 : bc0;
  float* S = dir ? S1 : S0;
  const int tid = threadIdx.x;
  const int lane = tid & 63, wave = tid >> 6;
  const int n = lane & 15, cg = lane >> 4;
  const int cl = wave * 4 + cg;        // local channel 0..15
  const int c = ct * 16 + cl;
  const float a2 = A2[c * 16 + n];
  const float dpc = Dp[c];
  const size_t base = (size_t)b << 10;
  __shared__ __attribute__((aligned(16))) float sd[2][16][20];   // [cl][t]
  __shared__ __attribute__((aligned(16))) float su[2][16][20];
  __shared__ __attribute__((aligned(16))) float sz[2][16][20];
  __shared__ __attribute__((aligned(16))) float sbc[2][32][20];  // [col][t]
  const int li = tid >> 4, lj = tid & 15;   // staging: li=t, lj=c (coalesced)
  const int bi = tid >> 5, bj = tid & 31;
  float rd, ru, rz, rb0, rb1;
  auto issue = [&](int s0) {
    size_t row = base + s0 + li;
    rd = del[row * 384 + ct * 16 + lj];
    ru = uu[row * 384 + ct * 16 + lj];
    int t = dir ? (1023 - (s0 + li)) : (s0 + li);
    rz = xz[(base + t) * 768 + 384 + ct * 16 + lj];
    rb0 = bc[(base + s0 + bi) * 32 + bj];
    rb1 = bc[(base + s0 + bi + 8) * 32 + bj];
  };
  auto commit = [&](int buf) {
    sd[buf][lj][li] = rd; su[buf][lj][li] = ru; sz[buf][lj][li] = rz;
    sbc[buf][bj][bi] = rb0; sbc[buf][bj][bi + 8] = rb1;
  };
  issue(0); commit(0);
  float h = 0.f;
  for (int ch = 0; ch < 64; ++ch) {
    const int cur = ch & 1;
    const int s0 = ch * 16;
    if (ch + 1 < 64) issue((ch + 1) * 16);
    __syncthreads();
    // batch-load this lane's 16 steps (4x ds_read_b128 per operand)
    f32x4 dv[4], uv4[4], bmv[4], cmv[4];
    #pragma unroll
    for (int r = 0; r < 4; ++r) {
      dv[r]  = *(const f32x4*)&sd[cur][cl][r * 4];
      uv4[r] = *(const f32x4*)&su[cur][cl][r * 4];
      bmv[r] = *(const f32x4*)&sbc[cur][n][r * 4];
      cmv[r] = *(const f32x4*)&sbc[cur][16 + n][r * 4];
    }
    // serial core: 16 chained FMAs (dA/dBu precomputed by scheduler)
    float p[16];
    #pragma unroll
    for (int i = 0; i < 16; ++i) {
      float dd = dv[i >> 2][i & 3];
      float uv = uv4[i >> 2][i & 3];
      float bm = bmv[i >> 2][i & 3];
      float dA = __builtin_amdgcn_exp2f(dd * a2);
      h = fmaf(dA, h, dd * uv * bm);
      p[i] = h * cmv[i >> 2][i & 3];
    }
    // distributed butterfly: y[t] = sum_n p_n[t]; lane n ends with t=n.
    float q8[8];
    #pragma unroll
    for (int j = 0; j < 8; ++j) {
      float send = (n & 8) ? p[j] : p[j + 8];
      float recv = __shfl_xor(send, 8);
      float keep = (n & 8) ? p[j + 8] : p[j];
      q8[j] = keep + recv;
    }
    float q4[4];
    #pragma unroll
    for (int j = 0; j < 4; ++j) {
      float send = (n & 4) ? q8[j] : q8[j + 4];
      float recv = __shfl_xor(send, 4);
      float keep = (n & 4) ? q8[j + 4] : q8[j];
      q4[j] = keep + recv;
    }
    float q2[2];
    #pragma unroll
    for (int j = 0; j < 2; ++j) {
      float send = (n & 2) ? q4[j] : q4[j + 2];
      float recv = __shfl_xor(send, 2);
      float keep = (n & 2) ? q4[j + 2] : q4[j];
      q2[j] = keep + recv;
    }
    float send = (n & 1) ? q2[0] : q2[1];
    float recv = __shfl_xor(send, 1);
    float keep = (n & 1) ? q2[1] : q2[0];
    float ysum = keep + recv;
    // gate + store: lane n owns timestep s0+n of channel c
    float uvn = su[cur][cl][n];
    float zz  = sz[cur][cl][n];
    float sig = __builtin_amdgcn_rcpf(1.f + __builtin_amdgcn_exp2f(-zz * L2E));
    float y = (ysum + uvn * dpc) * (zz * sig);
    int s = s0 + n;
    int t = dir ? (1023 - s) : s;
    S[(base + t) * 384 + c] = y;
    if (ch + 1 < 64) commit(cur ^ 1);
  }
}

// ---------------- Ssum = bf16(S0 + S1) ------------------------------------
__global__ __launch_bounds__(256) void ssum_k(
    const float* __restrict__ S0, const float* __restrict__ S1,
    unsigned short* __restrict__ Sb) {
  int i = blockIdx.x * 256 + threadIdx.x;
  float4 a = ((const float4*)S0)[i];
  float4 b = ((const float4*)S1)[i];
  ushort4 r;
  r.x = f2bf(a.x + b.x); r.y = f2bf(a.y + b.y);
  r.z = f2bf(a.z + b.z); r.w = f2bf(a.w + b.w);
  ((ushort4*)Sb)[i] = r;
}

// ---------------- final: dwconv3x3 gate + transpose + residual ------------
__global__ __launch_bounds__(256) void final_k(
    const float* __restrict__ G, const float* __restrict__ xn,
    const float* __restrict__ x, const float* __restrict__ dww,
    const float* __restrict__ dwb, const float* __restrict__ rs,
    float* __restrict__ out) {
  __shared__ float tile[64][33];
  const int l0 = blockIdx.x * 32, c0 = blockIdx.y * 64, b = blockIdx.z;
  const int tid = threadIdx.x;
  {
    const int cj = tid & 63, li = tid >> 6;
    const int c = c0 + cj;
    float w[9];
    #pragma unroll
    for (int q = 0; q < 9; ++q) w[q] = dww[c * 9 + q];
    const float bb = dwb[c];
    for (int p = 0; p < 8; ++p) {
      int l = l0 + p * 4 + li;
      int hh = l >> 5, ww = l & 31;
      float acc = bb;
      #pragma unroll
      for (int di = -1; di <= 1; ++di) {
        int h2 = hh + di; if (h2 < 0 || h2 > 31) continue;
        #pragma unroll
        for (int dj = -1; dj <= 1; ++dj) {
          int w2 = ww + dj; if (w2 < 0 || w2 > 31) continue;
          acc += xn[(size_t)((b << 10) + h2 * 32 + w2) * 384 + c] * w[(di + 1) * 3 + dj + 1];
        }
      }
      size_t ri = (size_t)((b << 10) + l) * 384 + c;
      float xv = xn[ri];
      float F = G[ri] + xv / (1.f + expf(-acc));
      tile[cj][p * 4 + li] = F;
    }
  }
  __syncthreads();
  {
    const int lw = tid & 31, cr = tid >> 5;
    const float rsv = rs[0];
    for (int p = 0; p < 8; ++p) {
      int c = c0 + p * 8 + cr;
      size_t o = ((size_t)(b * 384 + c) << 10) + l0 + lw;
      out[o] = x[o] + rsv * tile[p * 8 + cr][lw];
    }
  }
}

// ---------------- host ----------------------------------------------------
extern "C" void kernel_launch(void* const* d_in, const int* in_sizes, int n_in,
                              void* d_out, int out_size, void* d_ws, size_t ws_size,
                              hipStream_t stream) {
  const float* x         = (const float*)d_in[0];
  const float* norm_w    = (const float*)d_in[1];
  const float* in_proj_w = (const float*)d_in[2];
  const float* conv1d_w  = (const float*)d_in[3];
  const float* conv1d_b  = (const float*)d_in[4];
  const float* x_proj_w  = (const float*)d_in[5];
  const float* dt_proj_w = (const float*)d_in[6];
  const float* dt_proj_b = (const float*)d_in[7];
  const float* A_log     = (const float*)d_in[8];
  const float* D_param   = (const float*)d_in[9];
  const float* out_proj_w= (const float*)d_in[10];
  const float* scale_mod = (const float*)d_in[11];
  const float* dw_w      = (const float*)d_in[12];
  const float* dw_b      = (const float*)d_in[13];
  const float* res_scale = (const float*)d_in[14];
  float* out = (float*)d_out;

  char* base = (char*)d_ws;
  size_t off = 0;
  auto alloc = [&](size_t bytes) {
    off = (off + 255) & ~(size_t)255;
    void* p = base + off;
    off += bytes;
    return p;
  };
  const size_t F_BLC  = (size_t)8192 * 384 * 4;
  const size_t B_BLC  = (size_t)8192 * 384 * 2;

  float*          xn_f = (float*)alloc(F_BLC);
  unsigned short* xn_b = (unsigned short*)alloc(B_BLC);
  float*          xz   = (float*)alloc((size_t)8192 * 768 * 4);
  float*          u_f0 = (float*)alloc(F_BLC);
  float*          u_f1 = (float*)alloc(F_BLC);
  unsigned short* u_b0 = (unsigned short*)alloc(B_BLC);
  unsigned short* u_b1 = (unsigned short*)alloc(B_BLC);
  unsigned short* dtp0 = (unsigned short*)alloc((size_t)8192 * 32 * 2);
  unsigned short* dtp1 = (unsigned short*)alloc((size_t)8192 * 32 * 2);
  float*          bc0  = (float*)alloc((size_t)8192 * 32 * 4);
  float*          bc1  = (float*)alloc((size_t)8192 * 32 * 4);
  float*          de0  = (float*)alloc(F_BLC);
  float*          de1  = (float*)alloc(F_BLC);
  float*          S0   = (float*)alloc(F_BLC);
  float*          S1   = (float*)alloc(F_BLC);
  unsigned short* W_in = (unsigned short*)alloc((size_t)768 * 384 * 2);
  unsigned short* W_x  = (unsigned short*)alloc((size_t)64 * 384 * 2);
  unsigned short* W_dt = (unsigned short*)alloc((size_t)384 * 32 * 2);
  unsigned short* W_out= (unsigned short*)alloc((size_t)384 * 384 * 2);
  float*          A2   = (float*)alloc((size_t)384 * 16 * 4);
  unsigned short* Ssum = (unsigned short*)de0;
  float*          G    = xz;

  prep_k<<<dim3(1152, 5), 256, 0, stream>>>(in_proj_w, x_proj_w, dt_proj_w,
                                            out_proj_w, A_log,
                                            W_in, W_x, W_dt, W_out, A2);
  rmsnorm_k<<<dim3(32, 8), 256, 0, stream>>>(x, norm_w, xn_f, xn_b);
  gemm_k<0><<<dim3(128, 12), 256, 0, stream>>>(xn_b, W_in, 384, 768, xz,
                                               nullptr, nullptr, nullptr);
  conv_silu_k<<<dim3(128, 8, 2), 384, 0, stream>>>(xz, conv1d_w, conv1d_b,
                                                   u_f0, u_f1, u_b0, u_b1);
  gemm_k<1><<<dim3(128, 1), 256, 0, stream>>>(u_b0, W_x, 384, 64, bc0, dtp0,
                                              nullptr, nullptr);
  gemm_k<1><<<dim3(128, 1), 256, 0, stream>>>(u_b1, W_x, 384, 64, bc1, dtp1,
                                              nullptr, nullptr);
  gemm_k<2><<<dim3(128, 6), 256, 0, stream>>>(dtp0, W_dt, 32, 384, de0,
                                              nullptr, dt_proj_b, nullptr);
  gemm_k<2><<<dim3(128, 6), 256, 0, stream>>>(dtp1, W_dt, 32, 384, de1,
                                              nullptr, dt_proj_b, nullptr);
  scan_k<<<dim3(24, 8, 2), 256, 0, stream>>>(de0, de1, u_f0, u_f1, bc0, bc1,
                                             xz, A2, D_param, S0, S1);
  ssum_k<<<3072, 256, 0, stream>>>(S0, S1, Ssum);
  gemm_k<3><<<dim3(128, 6), 256, 0, stream>>>(Ssum, W_out, 384, 384, G,
                                              nullptr, nullptr, scale_mod);
  final_k<<<dim3(32, 6, 8), 256, 0, stream>>>(G, xn_f, x, dw_w, dw_b,
                                              res_scale, out);
}

// Round 3
// 286.319 us; speedup vs baseline: 2.0274x; 1.0106x over previous
//
#include <hip/hip_runtime.h>
#include <hip/hip_bf16.h>

// HiMambaBottleneck: B=8, C=384, H=W=32, L=1024, BL=8192, dt_rank=24, N=16.
//  - in_proj GEMM once (pointwise => shared fwd/bwd); out_proj once on sum.
//  - scan: 2-pass segmented (8 x 128) for 8x parallelism; chunk-of-16 core.
//  - big GEMMs: m97 structure (128^2 tile, BK=32, global_load_lds w=16).

typedef __attribute__((ext_vector_type(8))) short bf16x8;
typedef __attribute__((ext_vector_type(4))) float f32x4;

#define L2E 1.44269504088896340736f

static __device__ __forceinline__ unsigned short f2bf(float f) {
  unsigned int u = __builtin_bit_cast(unsigned int, f);
  u += 0x7fff + ((u >> 16) & 1);  // RNE
  return (unsigned short)(u >> 16);
}

#define GLOAD_LDS16(g, l)                                             \
  __builtin_amdgcn_global_load_lds(                                   \
      (const __attribute__((address_space(1))) unsigned int*)(g),     \
      (__attribute__((address_space(3))) unsigned int*)(l), 16, 0, 0)

// ---------------- prep: weights -> bf16 (padded), A2 table ----------------
__global__ __launch_bounds__(256) void prep_k(
    const float* __restrict__ in_w, const float* __restrict__ x_w,
    const float* __restrict__ dt_w, const float* __restrict__ out_w,
    const float* __restrict__ A_log,
    unsigned short* __restrict__ W_in, unsigned short* __restrict__ W_x,
    unsigned short* __restrict__ W_dt, unsigned short* __restrict__ W_out,
    float* __restrict__ A2) {
  int idx = blockIdx.x * 256 + threadIdx.x;
  switch (blockIdx.y) {
    case 0: if (idx < 768 * 384) W_in[idx] = f2bf(in_w[idx]); break;
    case 1: if (idx < 64 * 384) { int n = idx / 384, k = idx - n * 384;
              W_x[idx] = f2bf(n < 56 ? x_w[n * 384 + k] : 0.f); } break;
    case 2: if (idx < 384 * 32) { int n = idx >> 5, k = idx & 31;
              W_dt[idx] = f2bf(k < 24 ? dt_w[n * 24 + k] : 0.f); } break;
    case 3: if (idx < 384 * 384) W_out[idx] = f2bf(out_w[idx]); break;
    case 4: if (idx < 384 * 16) A2[idx] = -expf(A_log[idx]) * L2E; break;
  }
}

// ---------------- rmsnorm: x NCHW -> xn channels-last (f32 + bf16) --------
__global__ __launch_bounds__(256) void rmsnorm_k(
    const float* __restrict__ x, const float* __restrict__ nw,
    float* __restrict__ xn, unsigned short* __restrict__ xnb) {
  const int b = blockIdx.y;
  const int l0 = blockIdx.x * 32;
  const int tid = threadIdx.x;
  const int ci = tid >> 5, lw = tid & 31;
  __shared__ float part[8][33];
  __shared__ float nf[32];
  __shared__ float t64[64][33];
  float acc = 0.f;
  for (int cc = ci; cc < 384; cc += 8) {
    float v = x[(((size_t)(b * 384 + cc)) << 10) + l0 + lw];
    acc = fmaf(v, v, acc);
  }
  part[ci][lw] = acc;
  __syncthreads();
  if (tid < 32) {
    float s = part[0][tid] + part[1][tid] + part[2][tid] + part[3][tid] +
              part[4][tid] + part[5][tid] + part[6][tid] + part[7][tid];
    nf[tid] = rsqrtf(s * (1.f / 384.f) + 1e-6f);
  }
  __syncthreads();
  const int cr = tid >> 5;
  const int cj = tid & 63, lr = tid >> 6;
  for (int cc = 0; cc < 6; ++cc) {
    #pragma unroll
    for (int k = 0; k < 8; ++k) {
      int cp = cr + k * 8;
      int c = cc * 64 + cp;
      float v = x[(((size_t)(b * 384 + c)) << 10) + l0 + lw];
      t64[cp][lw] = v * nf[lw] * nw[c];
    }
    __syncthreads();
    #pragma unroll
    for (int k2 = 0; k2 < 8; ++k2) {
      int ll = lr + 4 * k2;
      float val = t64[cj][ll];
      size_t a = ((size_t)((b << 10) + l0 + ll)) * 384 + cc * 64 + cj;
      xn[a] = val;
      xnb[a] = f2bf(val);
    }
    __syncthreads();
  }
}

// ---------------- 128^2 MFMA GEMM (m97 structure): C = A[M,K]*W[N,K]^T ----
// 4 waves 2x2, BK=32, global_load_lds width=16, linear LDS, 2 barriers/step.
template <int EPI>  // 0: plain f32 out; 3: * scale
__global__ __launch_bounds__(256) void gemm128_k(
    const unsigned short* __restrict__ A, const unsigned short* __restrict__ Bw,
    int K, int N, float* __restrict__ out0, const float* __restrict__ scale) {
  __shared__ unsigned short As[128 * 32];
  __shared__ unsigned short Bs[128 * 32];
  const int m0 = blockIdx.x * 128, n0 = blockIdx.y * 128;
  const int tid = threadIdx.x;
  const int lane = tid & 63, wave = tid >> 6;
  const int wm = wave >> 1, wn = wave & 1;
  const int fr = lane & 15, ks = (lane >> 4) * 8;
  const int row = tid >> 2, colseg = (tid & 3) * 8;
  const unsigned short* pA0 = A + (size_t)(m0 + row) * K + colseg;
  const unsigned short* pA1 = A + (size_t)(m0 + 64 + row) * K + colseg;
  const unsigned short* pB0 = Bw + (size_t)(n0 + row) * K + colseg;
  const unsigned short* pB1 = Bw + (size_t)(n0 + 64 + row) * K + colseg;
  unsigned short* lA0 = As + wave * 512;          // 64 slots * 8 ushorts
  unsigned short* lA1 = As + 2048 + wave * 512;
  unsigned short* lB0 = Bs + wave * 512;
  unsigned short* lB1 = Bs + 2048 + wave * 512;
  f32x4 acc[4][4] = {};
  for (int k0 = 0; k0 < K; k0 += 32) {
    __syncthreads();
    GLOAD_LDS16(pA0, lA0);
    GLOAD_LDS16(pA1, lA1);
    GLOAD_LDS16(pB0, lB0);
    GLOAD_LDS16(pB1, lB1);
    pA0 += 32; pA1 += 32; pB0 += 32; pB1 += 32;
    __syncthreads();
    bf16x8 af[4], bf[4];
    #pragma unroll
    for (int mi = 0; mi < 4; ++mi)
      af[mi] = *(const bf16x8*)&As[(wm * 64 + mi * 16 + fr) * 32 + ks];
    #pragma unroll
    for (int ni = 0; ni < 4; ++ni)
      bf[ni] = *(const bf16x8*)&Bs[(wn * 64 + ni * 16 + fr) * 32 + ks];
    #pragma unroll
    for (int mi = 0; mi < 4; ++mi)
      #pragma unroll
      for (int ni = 0; ni < 4; ++ni)
        acc[mi][ni] = __builtin_amdgcn_mfma_f32_16x16x32_bf16(af[mi], bf[ni], acc[mi][ni], 0, 0, 0);
  }
  const float sc = (EPI == 3) ? scale[0] : 1.f;
  #pragma unroll
  for (int mi = 0; mi < 4; ++mi)
    #pragma unroll
    for (int ni = 0; ni < 4; ++ni)
      #pragma unroll
      for (int j = 0; j < 4; ++j) {
        int m = m0 + wm * 64 + mi * 16 + (lane >> 4) * 4 + j;
        int n = n0 + wn * 64 + ni * 16 + fr;
        out0[(size_t)m * N + n] = acc[mi][ni][j] * sc;
      }
}

// ---------------- small GEMM 64^2 (dir-merged): EPI1 x_proj, EPI2 dt_proj -
template <int EPI>
__global__ __launch_bounds__(256) void gemm_k(
    const unsigned short* __restrict__ A0u, const unsigned short* __restrict__ A1u,
    const unsigned short* __restrict__ Bw, int K, int N,
    float* __restrict__ o0a, float* __restrict__ o0b,
    unsigned short* __restrict__ oba, unsigned short* __restrict__ obb,
    const float* __restrict__ bias) {
  const unsigned short* A = blockIdx.z ? A1u : A0u;
  float* out0 = blockIdx.z ? o0b : o0a;
  unsigned short* outb = blockIdx.z ? obb : oba;
  __shared__ unsigned short As[64][40];
  __shared__ unsigned short Bs[64][40];
  const int m0 = blockIdx.x * 64, n0 = blockIdx.y * 64;
  const int tid = threadIdx.x;
  const int lane = tid & 63, wave = tid >> 6;
  const int wm = wave >> 1, wn = wave & 1;
  const int lrow = tid >> 2, lseg = (tid & 3) * 8;
  const int fr = lane & 15, ks = (lane >> 4) * 8;
  f32x4 acc[2][2] = {};
  for (int k0 = 0; k0 < K; k0 += 32) {
    __syncthreads();
    *(bf16x8*)&As[lrow][lseg] = *(const bf16x8*)&A[(size_t)(m0 + lrow) * K + k0 + lseg];
    *(bf16x8*)&Bs[lrow][lseg] = *(const bf16x8*)&Bw[(size_t)(n0 + lrow) * K + k0 + lseg];
    __syncthreads();
    bf16x8 a0 = *(const bf16x8*)&As[wm * 32 + fr][ks];
    bf16x8 a1 = *(const bf16x8*)&As[wm * 32 + 16 + fr][ks];
    bf16x8 b0 = *(const bf16x8*)&Bs[wn * 32 + fr][ks];
    bf16x8 b1 = *(const bf16x8*)&Bs[wn * 32 + 16 + fr][ks];
    acc[0][0] = __builtin_amdgcn_mfma_f32_16x16x32_bf16(a0, b0, acc[0][0], 0, 0, 0);
    acc[0][1] = __builtin_amdgcn_mfma_f32_16x16x32_bf16(a0, b1, acc[0][1], 0, 0, 0);
    acc[1][0] = __builtin_amdgcn_mfma_f32_16x16x32_bf16(a1, b0, acc[1][0], 0, 0, 0);
    acc[1][1] = __builtin_amdgcn_mfma_f32_16x16x32_bf16(a1, b1, acc[1][1], 0, 0, 0);
  }
  #pragma unroll
  for (int mi = 0; mi < 2; ++mi)
    #pragma unroll
    for (int ni = 0; ni < 2; ++ni)
      #pragma unroll
      for (int j = 0; j < 4; ++j) {
        int m = m0 + wm * 32 + mi * 16 + (lane >> 4) * 4 + j;
        int n = n0 + wn * 32 + ni * 16 + (lane & 15);
        float v = acc[mi][ni][j];
        if (EPI == 1) {
          if (n < 24) outb[m * 32 + n] = f2bf(v);
          else if (n < 32) outb[m * 32 + n] = 0;
          if (n >= 24 && n < 56) out0[m * 32 + (n - 24)] = v;
        } else {
          float t = v + bias[n];
          out0[(size_t)m * N + n] = (t > 20.f) ? t : log1pf(expf(t));
        }
      }
}

// ---------------- causal depthwise conv1d + silu (both directions) --------
__global__ __launch_bounds__(384) void conv_silu_k(
    const float* __restrict__ xz, const float* __restrict__ cw,
    const float* __restrict__ cb,
    float* __restrict__ u0, float* __restrict__ u1,
    unsigned short* __restrict__ ub0, unsigned short* __restrict__ ub1) {
  const int st = blockIdx.x, b = blockIdx.y, dir = blockIdx.z;
  const int c = threadIdx.x;
  const int s0 = st * 8;
  const float w0 = cw[c * 4 + 0], w1 = cw[c * 4 + 1];
  const float w2 = cw[c * 4 + 2], w3 = cw[c * 4 + 3];
  const float bb = cb[c];
  float* uf = dir ? u1 : u0;
  unsigned short* ub = dir ? ub1 : ub0;
  float xv[11];
  #pragma unroll
  for (int k = 0; k < 11; ++k) {
    int j = s0 - 3 + k;
    float v = 0.f;
    if (j >= 0) {
      int t = dir ? (1023 - j) : j;
      v = xz[(size_t)((b << 10) + t) * 768 + c];
    }
    xv[k] = v;
  }
  #pragma unroll
  for (int s = 0; s < 8; ++s) {
    float a = bb + xv[s] * w0 + xv[s + 1] * w1 + xv[s + 2] * w2 + xv[s + 3] * w3;
    float uv = a * __builtin_amdgcn_rcpf(1.f + __builtin_amdgcn_exp2f(-a * L2E));
    size_t o = (size_t)((b << 10) + s0 + s) * 384 + c;
    uf[o] = uv;
    ub[o] = f2bf(uv);
  }
}

// ---------------- scan pass 1: per-segment (P = prod dA, h_local) ---------
// grid (24 ct, 8 b, 16 = dir*8+seg); 128 steps/segment in 8 chunks of 16.
__global__ __launch_bounds__(256) void scan1_k(
    const float* __restrict__ d0, const float* __restrict__ d1,
    const float* __restrict__ u0, const float* __restrict__ u1,
    const float* __restrict__ bc0, const float* __restrict__ bc1,
    const float* __restrict__ A2,
    float* __restrict__ Pseg, float* __restrict__ Hseg) {
  const int ct = blockIdx.x, b = blockIdx.y;
  const int dir = blockIdx.z >> 3, seg = blockIdx.z & 7;
  const float* del = dir ? d1 : d0;
  const float* uu  = dir ? u1 : u0;
  const float* bc  = dir ? bc1 : bc0;
  const int tid = threadIdx.x;
  const int lane = tid & 63, wave = tid >> 6;
  const int n = lane & 15, cg = lane >> 4;
  const int cl = wave * 4 + cg;
  const int c = ct * 16 + cl;
  const float a2 = A2[c * 16 + n];
  const size_t base = ((size_t)b << 10) + seg * 128;
  __shared__ __attribute__((aligned(16))) float sd[2][16][20];
  __shared__ __attribute__((aligned(16))) float su[2][16][20];
  __shared__ __attribute__((aligned(16))) float sB[2][16][20];
  const int li = tid >> 4, lj = tid & 15;
  float rd, ru, rb;
  auto issue = [&](int s0) {
    size_t rowi = base + s0 + li;
    rd = del[rowi * 384 + ct * 16 + lj];
    ru = uu [rowi * 384 + ct * 16 + lj];
    rb = bc [rowi * 32 + lj];
  };
  auto commit = [&](int buf) {
    sd[buf][lj][li] = rd; su[buf][lj][li] = ru; sB[buf][lj][li] = rb;
  };
  issue(0); commit(0);
  float h = 0.f, P = 1.f;
  for (int ch = 0; ch < 8; ++ch) {
    const int cur = ch & 1;
    if (ch + 1 < 8) issue((ch + 1) * 16);
    __syncthreads();
    f32x4 dv[4], uv4[4], bmv[4];
    #pragma unroll
    for (int r = 0; r < 4; ++r) {
      dv[r]  = *(const f32x4*)&sd[cur][cl][r * 4];
      uv4[r] = *(const f32x4*)&su[cur][cl][r * 4];
      bmv[r] = *(const f32x4*)&sB[cur][n][r * 4];
    }
    #pragma unroll
    for (int i = 0; i < 16; ++i) {
      float dd = dv[i >> 2][i & 3];
      float uv = uv4[i >> 2][i & 3];
      float bm = bmv[i >> 2][i & 3];
      float dA = __builtin_amdgcn_exp2f(dd * a2);
      h = fmaf(dA, h, dd * uv * bm);
      P *= dA;
    }
    if (ch + 1 < 8) { __syncthreads(); commit(cur ^ 1); }
  }
  size_t o = (size_t)((dir * 8 + b) * 8 + seg) * 6144 + c * 16 + n;
  Pseg[o] = P; Hseg[o] = h;
}

// ---------------- combine: h_in per segment (serial over 8 segs) ----------
__global__ __launch_bounds__(256) void scomb_k(
    const float* __restrict__ Pseg, const float* __restrict__ Hseg,
    float* __restrict__ Hin) {
  const int db = blockIdx.y;                   // dir*8+b
  const int r = blockIdx.x * 256 + threadIdx.x;  // c*16+n
  float h = 0.f;
  #pragma unroll
  for (int s = 0; s < 8; ++s) {
    size_t o = (size_t)(db * 8 + s) * 6144 + r;
    Hin[o] = h;
    h = Pseg[o] * h + Hseg[o];
  }
}

// ---------------- scan pass 2: full scan per segment, seeded --------------
__global__ __launch_bounds__(256) void scan2_k(
    const float* __restrict__ d0, const float* __restrict__ d1,
    const float* __restrict__ u0, const float* __restrict__ u1,
    const float* __restrict__ bc0, const float* __restrict__ bc1,
    const float* __restrict__ xz, const float* __restrict__ A2,
    const float* __restrict__ Dp, const float* __restrict__ Hin,
    float* __restrict__ S0, float* __restrict__ S1) {
  const int ct = blockIdx.x, b = blockIdx.y;
  const int dir = blockIdx.z >> 3, seg = blockIdx.z & 7;
  const float* del = dir ? d1 : d0;
  const float* uu  = dir ? u1 : u0;
  const float* bc  = dir ? bc1 : bc0;
  float* S = dir ? S1 : S0;
  const int tid = threadIdx.x;
  const int lane = tid & 63, wave = tid >> 6;
  const int n = lane & 15, cg = lane >> 4;
  const int cl = wave * 4 + cg;
  const int c = ct * 16 + cl;
  const float a2 = A2[c * 16 + n];
  const float dpc = Dp[c];
  const size_t base = (size_t)b << 10;
  const int segoff = seg * 128;
  __shared__ __attribute__((aligned(16))) float sd[2][16][20];
  __shared__ __attribute__((aligned(16))) float su[2][16][20];
  __shared__ __attribute__((aligned(16))) float sz[2][16][20];
  __shared__ __attribute__((aligned(16))) float sbc[2][32][20];
  const int li = tid >> 4, lj = tid & 15;
  const int bi = tid >> 5, bj = tid & 31;
  float rd, ru, rz, rb0, rb1;
  auto issue = [&](int s0) {
    size_t rowi = base + segoff + s0 + li;
    rd = del[rowi * 384 + ct * 16 + lj];
    ru = uu [rowi * 384 + ct * 16 + lj];
    int t = dir ? (1023 - (segoff + s0 + li)) : (segoff + s0 + li);
    rz = xz[(base + t) * 768 + 384 + ct * 16 + lj];
    rb0 = bc[(base + segoff + s0 + bi) * 32 + bj];
    rb1 = bc[(base + segoff + s0 + bi + 8) * 32 + bj];
  };
  auto commit = [&](int buf) {
    sd[buf][lj][li] = rd; su[buf][lj][li] = ru; sz[buf][lj][li] = rz;
    sbc[buf][bj][bi] = rb0; sbc[buf][bj][bi + 8] = rb1;
  };
  issue(0); commit(0);
  float h = Hin[(size_t)((dir * 8 + b) * 8 + seg) * 6144 + c * 16 + n];
  for (int ch = 0; ch < 8; ++ch) {
    const int cur = ch & 1;
    if (ch + 1 < 8) issue((ch + 1) * 16);
    __syncthreads();
    f32x4 dv[4], uv4[4], bmv[4], cmv[4];
    #pragma unroll
    for (int r = 0; r < 4; ++r) {
      dv[r]  = *(const f32x4*)&sd[cur][cl][r * 4];
      uv4[r] = *(const f32x4*)&su[cur][cl][r * 4];
      bmv[r] = *(const f32x4*)&sbc[cur][n][r * 4];
      cmv[r] = *(const f32x4*)&sbc[cur][16 + n][r * 4];
    }
    float p[16];
    #pragma unroll
    for (int i = 0; i < 16; ++i) {
      float dd = dv[i >> 2][i & 3];
      float uv = uv4[i >> 2][i & 3];
      float bm = bmv[i >> 2][i & 3];
      float dA = __builtin_amdgcn_exp2f(dd * a2);
      h = fmaf(dA, h, dd * uv * bm);
      p[i] = h * cmv[i >> 2][i & 3];
    }
    float q8[8];
    #pragma unroll
    for (int j = 0; j < 8; ++j) {
      float send = (n & 8) ? p[j] : p[j + 8];
      float recv = __shfl_xor(send, 8);
      float keep = (n & 8) ? p[j + 8] : p[j];
      q8[j] = keep + recv;
    }
    float q4[4];
    #pragma unroll
    for (int j = 0; j < 4; ++j) {
      float send = (n & 4) ? q8[j] : q8[j + 4];
      float recv = __shfl_xor(send, 4);
      float keep = (n & 4) ? q8[j + 4] : q8[j];
      q4[j] = keep + recv;
    }
    float q2[2];
    #pragma unroll
    for (int j = 0; j < 2; ++j) {
      float send = (n & 2) ? q4[j] : q4[j + 2];
      float recv = __shfl_xor(send, 2);
      float keep = (n & 2) ? q4[j + 2] : q4[j];
      q2[j] = keep + recv;
    }
    float send = (n & 1) ? q2[0] : q2[1];
    float recv = __shfl_xor(send, 1);
    float keep = (n & 1) ? q2[1] : q2[0];
    float ysum = keep + recv;
    float uvn = su[cur][cl][n];
    float zz  = sz[cur][cl][n];
    float sig = __builtin_amdgcn_rcpf(1.f + __builtin_amdgcn_exp2f(-zz * L2E));
    float y = (ysum + uvn * dpc) * (zz * sig);
    int s = segoff + ch * 16 + n;
    int t = dir ? (1023 - s) : s;
    S[(base + t) * 384 + c] = y;
    if (ch + 1 < 8) { __syncthreads(); commit(cur ^ 1); }
  }
}

// ---------------- Ssum = bf16(S0 + S1) ------------------------------------
__global__ __launch_bounds__(256) void ssum_k(
    const float* __restrict__ S0, const float* __restrict__ S1,
    unsigned short* __restrict__ Sb) {
  int i = blockIdx.x * 256 + threadIdx.x;
  float4 a = ((const float4*)S0)[i];
  float4 b = ((const float4*)S1)[i];
  ushort4 r;
  r.x = f2bf(a.x + b.x); r.y = f2bf(a.y + b.y);
  r.z = f2bf(a.z + b.z); r.w = f2bf(a.w + b.w);
  ((ushort4*)Sb)[i] = r;
}

// ---------------- final: dwconv3x3 gate + transpose + residual ------------
__global__ __launch_bounds__(256) void final_k(
    const float* __restrict__ G, const float* __restrict__ xn,
    const float* __restrict__ x, const float* __restrict__ dww,
    const float* __restrict__ dwb, const float* __restrict__ rs,
    float* __restrict__ out) {
  __shared__ float tile[64][33];
  const int l0 = blockIdx.x * 32, c0 = blockIdx.y * 64, b = blockIdx.z;
  const int tid = threadIdx.x;
  {
    const int cj = tid & 63, li = tid >> 6;
    const int c = c0 + cj;
    float w[9];
    #pragma unroll
    for (int q = 0; q < 9; ++q) w[q] = dww[c * 9 + q];
    const float bb = dwb[c];
    for (int p = 0; p < 8; ++p) {
      int l = l0 + p * 4 + li;
      int hh = l >> 5, ww = l & 31;
      float acc = bb;
      #pragma unroll
      for (int di = -1; di <= 1; ++di) {
        int h2 = hh + di; if (h2 < 0 || h2 > 31) continue;
        #pragma unroll
        for (int dj = -1; dj <= 1; ++dj) {
          int w2 = ww + dj; if (w2 < 0 || w2 > 31) continue;
          acc += xn[(size_t)((b << 10) + h2 * 32 + w2) * 384 + c] * w[(di + 1) * 3 + dj + 1];
        }
      }
      size_t ri = (size_t)((b << 10) + l) * 384 + c;
      float xv = xn[ri];
      float F = G[ri] + xv / (1.f + expf(-acc));
      tile[cj][p * 4 + li] = F;
    }
  }
  __syncthreads();
  {
    const int lw = tid & 31, cr = tid >> 5;
    const float rsv = rs[0];
    for (int p = 0; p < 8; ++p) {
      int c = c0 + p * 8 + cr;
      size_t o = ((size_t)(b * 384 + c) << 10) + l0 + lw;
      out[o] = x[o] + rsv * tile[p * 8 + cr][lw];
    }
  }
}

// ---------------- host ----------------------------------------------------
extern "C" void kernel_launch(void* const* d_in, const int* in_sizes, int n_in,
                              void* d_out, int out_size, void* d_ws, size_t ws_size,
                              hipStream_t stream) {
  const float* x         = (const float*)d_in[0];
  const float* norm_w    = (const float*)d_in[1];
  const float* in_proj_w = (const float*)d_in[2];
  const float* conv1d_w  = (const float*)d_in[3];
  const float* conv1d_b  = (const float*)d_in[4];
  const float* x_proj_w  = (const float*)d_in[5];
  const float* dt_proj_w = (const float*)d_in[6];
  const float* dt_proj_b = (const float*)d_in[7];
  const float* A_log     = (const float*)d_in[8];
  const float* D_param   = (const float*)d_in[9];
  const float* out_proj_w= (const float*)d_in[10];
  const float* scale_mod = (const float*)d_in[11];
  const float* dw_w      = (const float*)d_in[12];
  const float* dw_b      = (const float*)d_in[13];
  const float* res_scale = (const float*)d_in[14];
  float* out = (float*)d_out;

  char* base = (char*)d_ws;
  size_t off = 0;
  auto alloc = [&](size_t bytes) {
    off = (off + 255) & ~(size_t)255;
    void* p = base + off;
    off += bytes;
    return p;
  };
  const size_t F_BLC  = (size_t)8192 * 384 * 4;
  const size_t B_BLC  = (size_t)8192 * 384 * 2;

  float*          xn_f = (float*)alloc(F_BLC);
  unsigned short* xn_b = (unsigned short*)alloc(B_BLC);
  float*          xz   = (float*)alloc((size_t)8192 * 768 * 4);
  float*          u_f0 = (float*)alloc(F_BLC);
  float*          u_f1 = (float*)alloc(F_BLC);
  unsigned short* u_b0 = (unsigned short*)alloc(B_BLC);
  unsigned short* u_b1 = (unsigned short*)alloc(B_BLC);
  unsigned short* dtp0 = (unsigned short*)alloc((size_t)8192 * 32 * 2);
  unsigned short* dtp1 = (unsigned short*)alloc((size_t)8192 * 32 * 2);
  float*          bc0  = (float*)alloc((size_t)8192 * 32 * 4);
  float*          bc1  = (float*)alloc((size_t)8192 * 32 * 4);
  float*          de0  = (float*)alloc(F_BLC);
  float*          de1  = (float*)alloc(F_BLC);
  float*          S0   = (float*)alloc(F_BLC);
  float*          S1   = (float*)alloc(F_BLC);
  float*          Pseg = (float*)alloc((size_t)786432 * 4);
  float*          Hseg = (float*)alloc((size_t)786432 * 4);
  float*          Hin  = (float*)alloc((size_t)786432 * 4);
  unsigned short* W_in = (unsigned short*)alloc((size_t)768 * 384 * 2);
  unsigned short* W_x  = (unsigned short*)alloc((size_t)64 * 384 * 2);
  unsigned short* W_dt = (unsigned short*)alloc((size_t)384 * 32 * 2);
  unsigned short* W_out= (unsigned short*)alloc((size_t)384 * 384 * 2);
  float*          A2   = (float*)alloc((size_t)384 * 16 * 4);
  unsigned short* Ssum = (unsigned short*)de0;
  float*          G    = xz;

  prep_k<<<dim3(1152, 5), 256, 0, stream>>>(in_proj_w, x_proj_w, dt_proj_w,
                                            out_proj_w, A_log,
                                            W_in, W_x, W_dt, W_out, A2);
  rmsnorm_k<<<dim3(32, 8), 256, 0, stream>>>(x, norm_w, xn_f, xn_b);
  gemm128_k<0><<<dim3(64, 6), 256, 0, stream>>>(xn_b, W_in, 384, 768, xz, nullptr);
  conv_silu_k<<<dim3(128, 8, 2), 384, 0, stream>>>(xz, conv1d_w, conv1d_b,
                                                   u_f0, u_f1, u_b0, u_b1);
  gemm_k<1><<<dim3(128, 1, 2), 256, 0, stream>>>(u_b0, u_b1, W_x, 384, 64,
                                                 bc0, bc1, dtp0, dtp1, nullptr);
  gemm_k<2><<<dim3(128, 6, 2), 256, 0, stream>>>(dtp0, dtp1, W_dt, 32, 384,
                                                 de0, de1, nullptr, nullptr,
                                                 dt_proj_b);
  scan1_k<<<dim3(24, 8, 16), 256, 0, stream>>>(de0, de1, u_f0, u_f1, bc0, bc1,
                                               A2, Pseg, Hseg);
  scomb_k<<<dim3(24, 16), 256, 0, stream>>>(Pseg, Hseg, Hin);
  scan2_k<<<dim3(24, 8, 16), 256, 0, stream>>>(de0, de1, u_f0, u_f1, bc0, bc1,
                                               xz, A2, D_param, Hin, S0, S1);
  ssum_k<<<3072, 256, 0, stream>>>(S0, S1, Ssum);
  gemm128_k<3><<<dim3(64, 3), 256, 0, stream>>>(Ssum, W_out, 384, 384, G,
                                                scale_mod);
  final_k<<<dim3(32, 6, 8), 256, 0, stream>>>(G, xn_f, x, dw_w, dw_b,
                                              res_scale, out);
}

// Round 4
// 263.624 us; speedup vs baseline: 2.2019x; 1.0861x over previous
//
#include <hip/hip_runtime.h>
#include <hip/hip_bf16.h>

// HiMambaBottleneck: B=8, C=384, H=W=32, L=1024, BL=8192, dt_rank=24, N=16.
//  - bf16 mid-pipeline (xz, u, de, S) to halve HBM traffic; f32 only for bc/G.
//  - rmsnorm folded: norm_w into W_in (prep), rsqrt factor nf into in_proj epi.
//  - scan: 2-pass segmented, 16 segs x 64 steps (6144 blocks, full occupancy).

typedef __attribute__((ext_vector_type(8))) short bf16x8;
typedef __attribute__((ext_vector_type(8))) unsigned short u16x8;
typedef __attribute__((ext_vector_type(4))) float f32x4;

#define L2E 1.44269504088896340736f

static __device__ __forceinline__ unsigned short f2bf(float f) {
  unsigned int u = __builtin_bit_cast(unsigned int, f);
  u += 0x7fff + ((u >> 16) & 1);  // RNE
  return (unsigned short)(u >> 16);
}
static __device__ __forceinline__ float bf2f(unsigned short u) {
  unsigned int v = (unsigned int)u << 16;
  return __builtin_bit_cast(float, v);
}

// ---------------- prep: weights -> bf16 (padded), A2 table ----------------
__global__ __launch_bounds__(256) void prep_k(
    const float* __restrict__ in_w, const float* __restrict__ x_w,
    const float* __restrict__ dt_w, const float* __restrict__ out_w,
    const float* __restrict__ A_log, const float* __restrict__ nw,
    unsigned short* __restrict__ W_in, unsigned short* __restrict__ W_x,
    unsigned short* __restrict__ W_dt, unsigned short* __restrict__ W_out,
    float* __restrict__ A2) {
  int idx = blockIdx.x * 256 + threadIdx.x;
  switch (blockIdx.y) {
    case 0: if (idx < 768 * 384) W_in[idx] = f2bf(in_w[idx] * nw[idx % 384]); break;
    case 1: if (idx < 64 * 384) { int n = idx / 384, k = idx - n * 384;
              W_x[idx] = f2bf(n < 56 ? x_w[n * 384 + k] : 0.f); } break;
    case 2: if (idx < 384 * 32) { int n = idx >> 5, k = idx & 31;
              W_dt[idx] = f2bf(k < 24 ? dt_w[n * 24 + k] : 0.f); } break;
    case 3: if (idx < 384 * 384) W_out[idx] = f2bf(out_w[idx]); break;
    case 4: if (idx < 384 * 16) A2[idx] = -expf(A_log[idx]) * L2E; break;
  }
}

// ---------------- transpose-lite: x NCHW -> xb (CL bf16) + nf[bl] ---------
__global__ __launch_bounds__(256) void transpose_k(
    const float* __restrict__ x, unsigned short* __restrict__ xb,
    float* __restrict__ nf) {
  const int b = blockIdx.y;
  const int l0 = blockIdx.x * 32;
  const int tid = threadIdx.x;
  const int cr = tid >> 5, lw = tid & 31;
  const int cj = tid & 63, lr = tid >> 6;
  __shared__ float t64[64][33];
  __shared__ float part[8][33];
  float acc = 0.f;
  for (int cc = 0; cc < 6; ++cc) {
    #pragma unroll
    for (int k = 0; k < 8; ++k) {
      int cp = k * 8 + cr;
      int c = cc * 64 + cp;
      float v = x[(((size_t)(b * 384 + c)) << 10) + l0 + lw];
      t64[cp][lw] = v;
      acc = fmaf(v, v, acc);
    }
    __syncthreads();
    #pragma unroll
    for (int k2 = 0; k2 < 8; ++k2) {
      int ll = lr + 4 * k2;
      xb[((size_t)((b << 10) + l0 + ll)) * 384 + cc * 64 + cj] = f2bf(t64[cj][ll]);
    }
    __syncthreads();
  }
  part[cr][lw] = acc;
  __syncthreads();
  if (tid < 32) {
    float s = part[0][tid] + part[1][tid] + part[2][tid] + part[3][tid] +
              part[4][tid] + part[5][tid] + part[6][tid] + part[7][tid];
    nf[(b << 10) + l0 + tid] = rsqrtf(s * (1.f / 384.f) + 1e-6f);
  }
}

// ---------------- 64^2 bf16 MFMA GEMM: C[M,N] = A[M,K] * W[N,K]^T ---------
// EPI 0: in_proj (xz bf16, x nf[m]); 1: x_proj (dtp bf16 + bc f32);
// EPI 2: dt_proj (+bias, softplus -> de bf16); 3: out_proj (f32 x scale).
template <int EPI>
__global__ __launch_bounds__(256) void gemm_k(
    const unsigned short* __restrict__ A0u, const unsigned short* __restrict__ A1u,
    const unsigned short* __restrict__ Bw, int K, int N,
    float* __restrict__ of0, float* __restrict__ of1,
    unsigned short* __restrict__ ob0, unsigned short* __restrict__ ob1,
    const float* __restrict__ aux) {
  const unsigned short* A = blockIdx.z ? A1u : A0u;
  float* outf = blockIdx.z ? of1 : of0;
  unsigned short* outb = blockIdx.z ? ob1 : ob0;
  __shared__ unsigned short As[64][40];
  __shared__ unsigned short Bs[64][40];
  const int m0 = blockIdx.x * 64, n0 = blockIdx.y * 64;
  const int tid = threadIdx.x;
  const int lane = tid & 63, wave = tid >> 6;
  const int wm = wave >> 1, wn = wave & 1;
  const int lrow = tid >> 2, lseg = (tid & 3) * 8;
  const int fr = lane & 15, ks = (lane >> 4) * 8;
  f32x4 acc[2][2] = {};
  for (int k0 = 0; k0 < K; k0 += 32) {
    __syncthreads();
    *(bf16x8*)&As[lrow][lseg] = *(const bf16x8*)&A[(size_t)(m0 + lrow) * K + k0 + lseg];
    *(bf16x8*)&Bs[lrow][lseg] = *(const bf16x8*)&Bw[(size_t)(n0 + lrow) * K + k0 + lseg];
    __syncthreads();
    bf16x8 a0 = *(const bf16x8*)&As[wm * 32 + fr][ks];
    bf16x8 a1 = *(const bf16x8*)&As[wm * 32 + 16 + fr][ks];
    bf16x8 b0 = *(const bf16x8*)&Bs[wn * 32 + fr][ks];
    bf16x8 b1 = *(const bf16x8*)&Bs[wn * 32 + 16 + fr][ks];
    acc[0][0] = __builtin_amdgcn_mfma_f32_16x16x32_bf16(a0, b0, acc[0][0], 0, 0, 0);
    acc[0][1] = __builtin_amdgcn_mfma_f32_16x16x32_bf16(a0, b1, acc[0][1], 0, 0, 0);
    acc[1][0] = __builtin_amdgcn_mfma_f32_16x16x32_bf16(a1, b0, acc[1][0], 0, 0, 0);
    acc[1][1] = __builtin_amdgcn_mfma_f32_16x16x32_bf16(a1, b1, acc[1][1], 0, 0, 0);
  }
  #pragma unroll
  for (int mi = 0; mi < 2; ++mi)
    #pragma unroll
    for (int ni = 0; ni < 2; ++ni)
      #pragma unroll
      for (int j = 0; j < 4; ++j) {
        int m = m0 + wm * 32 + mi * 16 + (lane >> 4) * 4 + j;
        int n = n0 + wn * 32 + ni * 16 + (lane & 15);
        float v = acc[mi][ni][j];
        if (EPI == 0) {                       // in_proj: * nf[m] -> xz bf16
          outb[(size_t)m * N + n] = f2bf(v * aux[m]);
        } else if (EPI == 1) {                // x_proj split
          if (n < 24) outb[m * 32 + n] = f2bf(v);
          else if (n < 32) outb[m * 32 + n] = 0;
          if (n >= 24 && n < 56) outf[m * 32 + (n - 24)] = v;
        } else if (EPI == 2) {                // dt_proj: softplus -> de bf16
          float t = v + aux[n];
          float sp = (t > 20.f) ? t : log1pf(expf(t));
          outb[(size_t)m * N + n] = f2bf(sp);
        } else {                              // out_proj: * scale -> G f32
          outf[(size_t)m * N + n] = v * aux[0];
        }
      }
}

// ---------------- causal depthwise conv1d + silu (both directions) --------
__global__ __launch_bounds__(384) void conv_silu_k(
    const unsigned short* __restrict__ xz, const float* __restrict__ cw,
    const float* __restrict__ cb,
    unsigned short* __restrict__ ub0, unsigned short* __restrict__ ub1) {
  const int st = blockIdx.x, b = blockIdx.y, dir = blockIdx.z;
  const int c = threadIdx.x;
  const int s0 = st * 8;
  const float w0 = cw[c * 4 + 0], w1 = cw[c * 4 + 1];
  const float w2 = cw[c * 4 + 2], w3 = cw[c * 4 + 3];
  const float bb = cb[c];
  unsigned short* ub = dir ? ub1 : ub0;
  float xv[11];
  #pragma unroll
  for (int k = 0; k < 11; ++k) {
    int j = s0 - 3 + k;
    float v = 0.f;
    if (j >= 0) {
      int t = dir ? (1023 - j) : j;
      v = bf2f(xz[(size_t)((b << 10) + t) * 768 + c]);
    }
    xv[k] = v;
  }
  #pragma unroll
  for (int s = 0; s < 8; ++s) {
    float a = bb + xv[s] * w0 + xv[s + 1] * w1 + xv[s + 2] * w2 + xv[s + 3] * w3;
    float uv = a * __builtin_amdgcn_rcpf(1.f + __builtin_amdgcn_exp2f(-a * L2E));
    ub[(size_t)((b << 10) + s0 + s) * 384 + c] = f2bf(uv);
  }
}

// ---------------- scan pass 1: per-segment (P = prod dA, h_local) ---------
// grid (24 ct, 8 b, 32 = dir*16+seg); 64 steps/segment in 4 chunks of 16.
__global__ __launch_bounds__(256) void scan1_k(
    const unsigned short* __restrict__ de0, const unsigned short* __restrict__ de1,
    const unsigned short* __restrict__ ub0, const unsigned short* __restrict__ ub1,
    const float* __restrict__ bc0, const float* __restrict__ bc1,
    const float* __restrict__ A2,
    float* __restrict__ Pseg, float* __restrict__ Hseg) {
  const int ct = blockIdx.x, b = blockIdx.y;
  const int dir = blockIdx.z >> 4, seg = blockIdx.z & 15;
  const unsigned short* del = dir ? de1 : de0;
  const unsigned short* uu  = dir ? ub1 : ub0;
  const float* bc  = dir ? bc1 : bc0;
  const int tid = threadIdx.x;
  const int lane = tid & 63, wave = tid >> 6;
  const int n = lane & 15, cg = lane >> 4;
  const int cl = wave * 4 + cg;
  const int c = ct * 16 + cl;
  const float a2 = A2[c * 16 + n];
  const size_t base = ((size_t)b << 10) + seg * 64;
  __shared__ __attribute__((aligned(16))) float sd[2][16][20];
  __shared__ __attribute__((aligned(16))) float sdu[2][16][20];
  __shared__ __attribute__((aligned(16))) float sB[2][16][20];
  const int li = tid >> 4, lj = tid & 15;
  unsigned short rd, ru; float rb;
  auto issue = [&](int s0) {
    size_t rowi = base + s0 + li;
    rd = del[rowi * 384 + ct * 16 + lj];
    ru = uu [rowi * 384 + ct * 16 + lj];
    rb = bc [rowi * 32 + lj];
  };
  auto commit = [&](int buf) {
    float dd = bf2f(rd), uv = bf2f(ru);
    sd[buf][lj][li] = dd; sdu[buf][lj][li] = dd * uv; sB[buf][lj][li] = rb;
  };
  issue(0); commit(0);
  float h = 0.f, P = 1.f;
  for (int ch = 0; ch < 4; ++ch) {
    const int cur = ch & 1;
    if (ch + 1 < 4) issue((ch + 1) * 16);
    __syncthreads();
    f32x4 dv[4], duv[4], bmv[4];
    #pragma unroll
    for (int r = 0; r < 4; ++r) {
      dv[r]  = *(const f32x4*)&sd[cur][cl][r * 4];
      duv[r] = *(const f32x4*)&sdu[cur][cl][r * 4];
      bmv[r] = *(const f32x4*)&sB[cur][n][r * 4];
    }
    #pragma unroll
    for (int i = 0; i < 16; ++i) {
      float dA = __builtin_amdgcn_exp2f(dv[i >> 2][i & 3] * a2);
      h = fmaf(dA, h, duv[i >> 2][i & 3] * bmv[i >> 2][i & 3]);
      P *= dA;
    }
    if (ch + 1 < 4) { __syncthreads(); commit(cur ^ 1); }
  }
  size_t o = (size_t)((dir * 8 + b) * 16 + seg) * 6144 + c * 16 + n;
  Pseg[o] = P; Hseg[o] = h;
}

// ---------------- combine: h_in per segment (serial over 16 segs) ---------
__global__ __launch_bounds__(256) void scomb_k(
    const float* __restrict__ Pseg, const float* __restrict__ Hseg,
    float* __restrict__ Hin) {
  const int db = blockIdx.y;                   // dir*8+b
  const int r = blockIdx.x * 256 + threadIdx.x;  // c*16+n
  float h = 0.f;
  #pragma unroll
  for (int s = 0; s < 16; ++s) {
    size_t o = (size_t)(db * 16 + s) * 6144 + r;
    Hin[o] = h;
    h = Pseg[o] * h + Hseg[o];
  }
}

// ---------------- scan pass 2: full scan per segment, seeded --------------
__global__ __launch_bounds__(256) void scan2_k(
    const unsigned short* __restrict__ de0, const unsigned short* __restrict__ de1,
    const unsigned short* __restrict__ ub0, const unsigned short* __restrict__ ub1,
    const float* __restrict__ bc0, const float* __restrict__ bc1,
    const unsigned short* __restrict__ xz, const float* __restrict__ A2,
    const float* __restrict__ Dp, const float* __restrict__ Hin,
    unsigned short* __restrict__ Sb0, unsigned short* __restrict__ Sb1) {
  const int ct = blockIdx.x, b = blockIdx.y;
  const int dir = blockIdx.z >> 4, seg = blockIdx.z & 15;
  const unsigned short* del = dir ? de1 : de0;
  const unsigned short* uu  = dir ? ub1 : ub0;
  const float* bc  = dir ? bc1 : bc0;
  unsigned short* S = dir ? Sb1 : Sb0;
  const int tid = threadIdx.x;
  const int lane = tid & 63, wave = tid >> 6;
  const int n = lane & 15, cg = lane >> 4;
  const int cl = wave * 4 + cg;
  const int c = ct * 16 + cl;
  const float a2 = A2[c * 16 + n];
  const float dpc = Dp[c];
  const size_t base = (size_t)b << 10;
  const int segoff = seg * 64;
  __shared__ __attribute__((aligned(16))) float sd[2][16][20];
  __shared__ __attribute__((aligned(16))) float sdu[2][16][20];
  __shared__ __attribute__((aligned(16))) float su[2][16][20];
  __shared__ __attribute__((aligned(16))) float sz[2][16][20];
  __shared__ __attribute__((aligned(16))) float sbc[2][32][20];
  const int li = tid >> 4, lj = tid & 15;
  const int bi = tid >> 5, bj = tid & 31;
  unsigned short rd, ru, rz; float rb0, rb1;
  auto issue = [&](int s0) {
    size_t rowi = base + segoff + s0 + li;
    rd = del[rowi * 384 + ct * 16 + lj];
    ru = uu [rowi * 384 + ct * 16 + lj];
    int t = dir ? (1023 - (segoff + s0 + li)) : (segoff + s0 + li);
    rz = xz[(base + t) * 768 + 384 + ct * 16 + lj];
    rb0 = bc[(base + segoff + s0 + bi) * 32 + bj];
    rb1 = bc[(base + segoff + s0 + bi + 8) * 32 + bj];
  };
  auto commit = [&](int buf) {
    float dd = bf2f(rd), uv = bf2f(ru);
    sd[buf][lj][li] = dd; sdu[buf][lj][li] = dd * uv;
    su[buf][lj][li] = uv; sz[buf][lj][li] = bf2f(rz);
    sbc[buf][bj][bi] = rb0; sbc[buf][bj][bi + 8] = rb1;
  };
  issue(0); commit(0);
  float h = Hin[(size_t)((dir * 8 + b) * 16 + seg) * 6144 + c * 16 + n];
  for (int ch = 0; ch < 4; ++ch) {
    const int cur = ch & 1;
    if (ch + 1 < 4) issue((ch + 1) * 16);
    __syncthreads();
    f32x4 dv[4], duv[4], bmv[4], cmv[4];
    #pragma unroll
    for (int r = 0; r < 4; ++r) {
      dv[r]  = *(const f32x4*)&sd[cur][cl][r * 4];
      duv[r] = *(const f32x4*)&sdu[cur][cl][r * 4];
      bmv[r] = *(const f32x4*)&sbc[cur][n][r * 4];
      cmv[r] = *(const f32x4*)&sbc[cur][16 + n][r * 4];
    }
    float p[16];
    #pragma unroll
    for (int i = 0; i < 16; ++i) {
      float dA = __builtin_amdgcn_exp2f(dv[i >> 2][i & 3] * a2);
      h = fmaf(dA, h, duv[i >> 2][i & 3] * bmv[i >> 2][i & 3]);
      p[i] = h * cmv[i >> 2][i & 3];
    }
    float q8[8];
    #pragma unroll
    for (int j = 0; j < 8; ++j) {
      float send = (n & 8) ? p[j] : p[j + 8];
      float recv = __shfl_xor(send, 8);
      float keep = (n & 8) ? p[j + 8] : p[j];
      q8[j] = keep + recv;
    }
    float q4[4];
    #pragma unroll
    for (int j = 0; j < 4; ++j) {
      float send = (n & 4) ? q8[j] : q8[j + 4];
      float recv = __shfl_xor(send, 4);
      float keep = (n & 4) ? q8[j + 4] : q8[j];
      q4[j] = keep + recv;
    }
    float q2[2];
    #pragma unroll
    for (int j = 0; j < 2; ++j) {
      float send = (n & 2) ? q4[j] : q4[j + 2];
      float recv = __shfl_xor(send, 2);
      float keep = (n & 2) ? q4[j + 2] : q4[j];
      q2[j] = keep + recv;
    }
    float send = (n & 1) ? q2[0] : q2[1];
    float recv = __shfl_xor(send, 1);
    float keep = (n & 1) ? q2[1] : q2[0];
    float ysum = keep + recv;
    float uvn = su[cur][cl][n];
    float zz  = sz[cur][cl][n];
    float sig = __builtin_amdgcn_rcpf(1.f + __builtin_amdgcn_exp2f(-zz * L2E));
    float y = (ysum + uvn * dpc) * (zz * sig);
    int s = segoff + ch * 16 + n;
    int t = dir ? (1023 - s) : s;
    S[(base + t) * 384 + c] = f2bf(y);
    if (ch + 1 < 4) { __syncthreads(); commit(cur ^ 1); }
  }
}

// ---------------- Ssum = bf16(S0 + S1) ------------------------------------
__global__ __launch_bounds__(256) void ssum_k(
    const unsigned short* __restrict__ S0, const unsigned short* __restrict__ S1,
    unsigned short* __restrict__ Sb) {
  int i = blockIdx.x * 256 + threadIdx.x;     // *8 elements
  u16x8 a = ((const u16x8*)S0)[i];
  u16x8 b = ((const u16x8*)S1)[i];
  u16x8 r;
  #pragma unroll
  for (int j = 0; j < 8; ++j) r[j] = f2bf(bf2f(a[j]) + bf2f(b[j]));
  ((u16x8*)Sb)[i] = r;
}

// ---------------- final: dwconv3x3 gate + transpose + residual ------------
__global__ __launch_bounds__(256) void final_k(
    const float* __restrict__ G, const unsigned short* __restrict__ xb,
    const float* __restrict__ nf, const float* __restrict__ nw,
    const float* __restrict__ x, const float* __restrict__ dww,
    const float* __restrict__ dwb, const float* __restrict__ rs,
    float* __restrict__ out) {
  __shared__ float tile[64][33];
  const int l0 = blockIdx.x * 32, c0 = blockIdx.y * 64, b = blockIdx.z;
  const int tid = threadIdx.x;
  {
    const int cj = tid & 63, li = tid >> 6;
    const int c = c0 + cj;
    float w[9];
    #pragma unroll
    for (int q = 0; q < 9; ++q) w[q] = dww[c * 9 + q];
    const float bb = dwb[c];
    const float nwc = nw[c];
    for (int p = 0; p < 8; ++p) {
      int l = l0 + p * 4 + li;
      int hh = l >> 5, ww = l & 31;
      float acc = bb;
      #pragma unroll
      for (int di = -1; di <= 1; ++di) {
        int h2 = hh + di; if (h2 < 0 || h2 > 31) continue;
        #pragma unroll
        for (int dj = -1; dj <= 1; ++dj) {
          int w2 = ww + dj; if (w2 < 0 || w2 > 31) continue;
          int lp = h2 * 32 + w2;
          float xnv = bf2f(xb[(size_t)((b << 10) + lp) * 384 + c]) *
                      nf[(b << 10) + lp] * nwc;
          acc += xnv * w[(di + 1) * 3 + dj + 1];
        }
      }
      size_t ri = (size_t)((b << 10) + l) * 384 + c;
      float xv = bf2f(xb[ri]) * nf[(b << 10) + l] * nwc;
      float F = G[ri] + xv / (1.f + expf(-acc));
      tile[cj][p * 4 + li] = F;
    }
  }
  __syncthreads();
  {
    const int lw = tid & 31, cr = tid >> 5;
    const float rsv = rs[0];
    for (int p = 0; p < 8; ++p) {
      int c = c0 + p * 8 + cr;
      size_t o = ((size_t)(b * 384 + c) << 10) + l0 + lw;
      out[o] = x[o] + rsv * tile[p * 8 + cr][lw];
    }
  }
}

// ---------------- host ----------------------------------------------------
extern "C" void kernel_launch(void* const* d_in, const int* in_sizes, int n_in,
                              void* d_out, int out_size, void* d_ws, size_t ws_size,
                              hipStream_t stream) {
  const float* x         = (const float*)d_in[0];
  const float* norm_w    = (const float*)d_in[1];
  const float* in_proj_w = (const float*)d_in[2];
  const float* conv1d_w  = (const float*)d_in[3];
  const float* conv1d_b  = (const float*)d_in[4];
  const float* x_proj_w  = (const float*)d_in[5];
  const float* dt_proj_w = (const float*)d_in[6];
  const float* dt_proj_b = (const float*)d_in[7];
  const float* A_log     = (const float*)d_in[8];
  const float* D_param   = (const float*)d_in[9];
  const float* out_proj_w= (const float*)d_in[10];
  const float* scale_mod = (const float*)d_in[11];
  const float* dw_w      = (const float*)d_in[12];
  const float* dw_b      = (const float*)d_in[13];
  const float* res_scale = (const float*)d_in[14];
  float* out = (float*)d_out;

  char* base = (char*)d_ws;
  size_t off = 0;
  auto alloc = [&](size_t bytes) {
    off = (off + 255) & ~(size_t)255;
    void* p = base + off;
    off += bytes;
    return p;
  };
  const size_t B_BLC = (size_t)8192 * 384 * 2;   // 6.29 MB bf16

  unsigned short* xb   = (unsigned short*)alloc(B_BLC);
  float*          nf   = (float*)alloc((size_t)8192 * 4);
  unsigned short* xz   = (unsigned short*)alloc((size_t)8192 * 768 * 2);
  unsigned short* u_b0 = (unsigned short*)alloc(B_BLC);
  unsigned short* u_b1 = (unsigned short*)alloc(B_BLC);
  unsigned short* dtp0 = (unsigned short*)alloc((size_t)8192 * 32 * 2);
  unsigned short* dtp1 = (unsigned short*)alloc((size_t)8192 * 32 * 2);
  float*          bc0  = (float*)alloc((size_t)8192 * 32 * 4);
  float*          bc1  = (float*)alloc((size_t)8192 * 32 * 4);
  unsigned short* de0  = (unsigned short*)alloc(B_BLC);
  unsigned short* de1  = (unsigned short*)alloc(B_BLC);
  unsigned short* Sb0  = (unsigned short*)alloc(B_BLC);
  unsigned short* Sb1  = (unsigned short*)alloc(B_BLC);
  float*          Pseg = (float*)alloc((size_t)1572864 * 4);
  float*          Hseg = (float*)alloc((size_t)1572864 * 4);
  float*          Hin  = (float*)alloc((size_t)1572864 * 4);
  unsigned short* W_in = (unsigned short*)alloc((size_t)768 * 384 * 2);
  unsigned short* W_x  = (unsigned short*)alloc((size_t)64 * 384 * 2);
  unsigned short* W_dt = (unsigned short*)alloc((size_t)384 * 32 * 2);
  unsigned short* W_out= (unsigned short*)alloc((size_t)384 * 384 * 2);
  float*          A2   = (float*)alloc((size_t)384 * 16 * 4);
  float*          G    = (float*)alloc((size_t)8192 * 384 * 4);
  unsigned short* Ssum = de0;   // de dead after scan2

  prep_k<<<dim3(1152, 5), 256, 0, stream>>>(in_proj_w, x_proj_w, dt_proj_w,
                                            out_proj_w, A_log, norm_w,
                                            W_in, W_x, W_dt, W_out, A2);
  transpose_k<<<dim3(32, 8), 256, 0, stream>>>(x, xb, nf);
  gemm_k<0><<<dim3(128, 12), 256, 0, stream>>>(xb, xb, W_in, 384, 768,
                                               nullptr, nullptr, xz, xz, nf);
  conv_silu_k<<<dim3(128, 8, 2), 384, 0, stream>>>(xz, conv1d_w, conv1d_b,
                                                   u_b0, u_b1);
  gemm_k<1><<<dim3(128, 1, 2), 256, 0, stream>>>(u_b0, u_b1, W_x, 384, 64,
                                                 bc0, bc1, dtp0, dtp1, nullptr);
  gemm_k<2><<<dim3(128, 6, 2), 256, 0, stream>>>(dtp0, dtp1, W_dt, 32, 384,
                                                 nullptr, nullptr, de0, de1,
                                                 dt_proj_b);
  scan1_k<<<dim3(24, 8, 32), 256, 0, stream>>>(de0, de1, u_b0, u_b1, bc0, bc1,
                                               A2, Pseg, Hseg);
  scomb_k<<<dim3(24, 16), 256, 0, stream>>>(Pseg, Hseg, Hin);
  scan2_k<<<dim3(24, 8, 32), 256, 0, stream>>>(de0, de1, u_b0, u_b1, bc0, bc1,
                                               xz, A2, D_param, Hin, Sb0, Sb1);
  ssum_k<<<1536, 256, 0, stream>>>(Sb0, Sb1, Ssum);
  gemm_k<3><<<dim3(128, 6), 256, 0, stream>>>(Ssum, Ssum, W_out, 384, 384,
                                              G, G, nullptr, nullptr, scale_mod);
  final_k<<<dim3(32, 6, 8), 256, 0, stream>>>(G, xb, nf, norm_w, x, dw_w, dw_b,
                                              res_scale, out);
}

// Round 5
// 257.754 us; speedup vs baseline: 2.2520x; 1.0228x over previous
//
#include <hip/hip_runtime.h>
#include <hip/hip_bf16.h>

// HiMambaBottleneck: B=8, C=384, H=W=32, L=1024, BL=8192, dt_rank=24, N=16.
//  - bf16 mid-pipeline; rmsnorm folded into W_in + in_proj epilogue.
//  - scan: 2-pass segmented 16x64; 32-channel/512-thread blocks (full-line
//    fetches); out_proj GEMM fuses S0+S1 sum in staging; final_k vectorized.

typedef __attribute__((ext_vector_type(8))) short bf16x8;
typedef __attribute__((ext_vector_type(8))) unsigned short u16x8;
typedef __attribute__((ext_vector_type(4))) float f32x4;

#define L2E 1.44269504088896340736f

static __device__ __forceinline__ unsigned short f2bf(float f) {
  unsigned int u = __builtin_bit_cast(unsigned int, f);
  u += 0x7fff + ((u >> 16) & 1);  // RNE
  return (unsigned short)(u >> 16);
}
static __device__ __forceinline__ float bf2f(unsigned short u) {
  unsigned int v = (unsigned int)u << 16;
  return __builtin_bit_cast(float, v);
}

// ---------------- prep: weights -> bf16 (padded), A2 table ----------------
__global__ __launch_bounds__(256) void prep_k(
    const float* __restrict__ in_w, const float* __restrict__ x_w,
    const float* __restrict__ dt_w, const float* __restrict__ out_w,
    const float* __restrict__ A_log, const float* __restrict__ nw,
    unsigned short* __restrict__ W_in, unsigned short* __restrict__ W_x,
    unsigned short* __restrict__ W_dt, unsigned short* __restrict__ W_out,
    float* __restrict__ A2) {
  int idx = blockIdx.x * 256 + threadIdx.x;
  switch (blockIdx.y) {
    case 0: if (idx < 768 * 384) W_in[idx] = f2bf(in_w[idx] * nw[idx % 384]); break;
    case 1: if (idx < 64 * 384) { int n = idx / 384, k = idx - n * 384;
              W_x[idx] = f2bf(n < 56 ? x_w[n * 384 + k] : 0.f); } break;
    case 2: if (idx < 384 * 32) { int n = idx >> 5, k = idx & 31;
              W_dt[idx] = f2bf(k < 24 ? dt_w[n * 24 + k] : 0.f); } break;
    case 3: if (idx < 384 * 384) W_out[idx] = f2bf(out_w[idx]); break;
    case 4: if (idx < 384 * 16) A2[idx] = -expf(A_log[idx]) * L2E; break;
  }
}

// ---------------- transpose-lite: x NCHW -> xb (CL bf16) + nf[bl] ---------
__global__ __launch_bounds__(256) void transpose_k(
    const float* __restrict__ x, unsigned short* __restrict__ xb,
    float* __restrict__ nf) {
  const int b = blockIdx.y;
  const int l0 = blockIdx.x * 32;
  const int tid = threadIdx.x;
  const int cr = tid >> 5, lw = tid & 31;
  const int cj = tid & 63, lr = tid >> 6;
  __shared__ float t64[64][33];
  __shared__ float part[8][33];
  float acc = 0.f;
  for (int cc = 0; cc < 6; ++cc) {
    #pragma unroll
    for (int k = 0; k < 8; ++k) {
      int cp = k * 8 + cr;
      int c = cc * 64 + cp;
      float v = x[(((size_t)(b * 384 + c)) << 10) + l0 + lw];
      t64[cp][lw] = v;
      acc = fmaf(v, v, acc);
    }
    __syncthreads();
    #pragma unroll
    for (int k2 = 0; k2 < 8; ++k2) {
      int ll = lr + 4 * k2;
      xb[((size_t)((b << 10) + l0 + ll)) * 384 + cc * 64 + cj] = f2bf(t64[cj][ll]);
    }
    __syncthreads();
  }
  part[cr][lw] = acc;
  __syncthreads();
  if (tid < 32) {
    float s = part[0][tid] + part[1][tid] + part[2][tid] + part[3][tid] +
              part[4][tid] + part[5][tid] + part[6][tid] + part[7][tid];
    nf[(b << 10) + l0 + tid] = rsqrtf(s * (1.f / 384.f) + 1e-6f);
  }
}

// ---------------- 64^2 bf16 MFMA GEMM: C[M,N] = A[M,K] * W[N,K]^T ---------
// grid: x = N-tiles (L2 A-reuse), y = M-tiles, z = dir.
// EPI 0: in_proj (-> xz bf16, x nf[m]); 1: x_proj (dtp bf16 + bc f32);
// EPI 2: dt_proj (+bias, softplus -> de bf16); 3: out_proj (f32 x scale).
// SUMIN: A-staging sums two bf16 sources (S0+S1).
template <int EPI, int SUMIN>
__global__ __launch_bounds__(256) void gemm_k(
    const unsigned short* __restrict__ A0u, const unsigned short* __restrict__ A1u,
    const unsigned short* __restrict__ Bw, int K, int N,
    float* __restrict__ of0, float* __restrict__ of1,
    unsigned short* __restrict__ ob0, unsigned short* __restrict__ ob1,
    const float* __restrict__ aux) {
  const unsigned short* A = blockIdx.z ? A1u : A0u;
  float* outf = blockIdx.z ? of1 : of0;
  unsigned short* outb = blockIdx.z ? ob1 : ob0;
  __shared__ unsigned short As[64][40];
  __shared__ unsigned short Bs[64][40];
  const int n0 = blockIdx.x * 64, m0 = blockIdx.y * 64;
  const int tid = threadIdx.x;
  const int lane = tid & 63, wave = tid >> 6;
  const int wm = wave >> 1, wn = wave & 1;
  const int lrow = tid >> 2, lseg = (tid & 3) * 8;
  const int fr = lane & 15, ks = (lane >> 4) * 8;
  f32x4 acc[2][2] = {};
  for (int k0 = 0; k0 < K; k0 += 32) {
    __syncthreads();
    if (SUMIN) {
      u16x8 va = *(const u16x8*)&A0u[(size_t)(m0 + lrow) * K + k0 + lseg];
      u16x8 vb = *(const u16x8*)&A1u[(size_t)(m0 + lrow) * K + k0 + lseg];
      u16x8 s;
      #pragma unroll
      for (int j = 0; j < 8; ++j) s[j] = f2bf(bf2f(va[j]) + bf2f(vb[j]));
      *(u16x8*)&As[lrow][lseg] = s;
    } else {
      *(bf16x8*)&As[lrow][lseg] = *(const bf16x8*)&A[(size_t)(m0 + lrow) * K + k0 + lseg];
    }
    *(bf16x8*)&Bs[lrow][lseg] = *(const bf16x8*)&Bw[(size_t)(n0 + lrow) * K + k0 + lseg];
    __syncthreads();
    bf16x8 a0 = *(const bf16x8*)&As[wm * 32 + fr][ks];
    bf16x8 a1 = *(const bf16x8*)&As[wm * 32 + 16 + fr][ks];
    bf16x8 b0 = *(const bf16x8*)&Bs[wn * 32 + fr][ks];
    bf16x8 b1 = *(const bf16x8*)&Bs[wn * 32 + 16 + fr][ks];
    acc[0][0] = __builtin_amdgcn_mfma_f32_16x16x32_bf16(a0, b0, acc[0][0], 0, 0, 0);
    acc[0][1] = __builtin_amdgcn_mfma_f32_16x16x32_bf16(a0, b1, acc[0][1], 0, 0, 0);
    acc[1][0] = __builtin_amdgcn_mfma_f32_16x16x32_bf16(a1, b0, acc[1][0], 0, 0, 0);
    acc[1][1] = __builtin_amdgcn_mfma_f32_16x16x32_bf16(a1, b1, acc[1][1], 0, 0, 0);
  }
  #pragma unroll
  for (int mi = 0; mi < 2; ++mi)
    #pragma unroll
    for (int ni = 0; ni < 2; ++ni)
      #pragma unroll
      for (int j = 0; j < 4; ++j) {
        int m = m0 + wm * 32 + mi * 16 + (lane >> 4) * 4 + j;
        int n = n0 + wn * 32 + ni * 16 + (lane & 15);
        float v = acc[mi][ni][j];
        if (EPI == 0) {                       // in_proj: * nf[m] -> xz bf16
          ob0[(size_t)m * N + n] = f2bf(v * aux[m]);
        } else if (EPI == 1) {                // x_proj split
          if (n < 24) outb[m * 32 + n] = f2bf(v);
          else if (n < 32) outb[m * 32 + n] = 0;
          if (n >= 24 && n < 56) outf[m * 32 + (n - 24)] = v;
        } else if (EPI == 2) {                // dt_proj: softplus -> de bf16
          float t = v + aux[n];
          float sp = (t > 20.f) ? t : log1pf(expf(t));
          outb[(size_t)m * N + n] = f2bf(sp);
        } else {                              // out_proj: * scale -> G f32
          of0[(size_t)m * N + n] = v * aux[0];
        }
      }
}

// ---------------- causal depthwise conv1d + silu (both directions) --------
__global__ __launch_bounds__(384) void conv_silu_k(
    const unsigned short* __restrict__ xz, const float* __restrict__ cw,
    const float* __restrict__ cb,
    unsigned short* __restrict__ ub0, unsigned short* __restrict__ ub1) {
  const int st = blockIdx.x, b = blockIdx.y, dir = blockIdx.z;
  const int c = threadIdx.x;
  const int s0 = st * 8;
  const float w0 = cw[c * 4 + 0], w1 = cw[c * 4 + 1];
  const float w2 = cw[c * 4 + 2], w3 = cw[c * 4 + 3];
  const float bb = cb[c];
  unsigned short* ub = dir ? ub1 : ub0;
  float xv[11];
  #pragma unroll
  for (int k = 0; k < 11; ++k) {
    int j = s0 - 3 + k;
    float v = 0.f;
    if (j >= 0) {
      int t = dir ? (1023 - j) : j;
      v = bf2f(xz[(size_t)((b << 10) + t) * 768 + c]);
    }
    xv[k] = v;
  }
  #pragma unroll
  for (int s = 0; s < 8; ++s) {
    float a = bb + xv[s] * w0 + xv[s + 1] * w1 + xv[s + 2] * w2 + xv[s + 3] * w3;
    float uv = a * __builtin_amdgcn_rcpf(1.f + __builtin_amdgcn_exp2f(-a * L2E));
    ub[(size_t)((b << 10) + s0 + s) * 384 + c] = f2bf(uv);
  }
}

// ---------------- scan pass 1: per-segment (P = prod dA, h_local) ---------
// grid (12 ct, 8 b, 32 = dir*16+seg); 512 thr = 32 ch x 16 n; 64B rows.
__global__ __launch_bounds__(512) void scan1_k(
    const unsigned short* __restrict__ de0, const unsigned short* __restrict__ de1,
    const unsigned short* __restrict__ ub0, const unsigned short* __restrict__ ub1,
    const float* __restrict__ bc0, const float* __restrict__ bc1,
    const float* __restrict__ A2,
    float* __restrict__ Pseg, float* __restrict__ Hseg) {
  const int ct = blockIdx.x, b = blockIdx.y;
  const int dir = blockIdx.z >> 4, seg = blockIdx.z & 15;
  const unsigned short* del = dir ? de1 : de0;
  const unsigned short* uu  = dir ? ub1 : ub0;
  const float* bc  = dir ? bc1 : bc0;
  const int tid = threadIdx.x;
  const int lane = tid & 63, wave = tid >> 6;
  const int n = lane & 15, cg = lane >> 4;
  const int cl = wave * 4 + cg;          // local channel 0..31
  const int c = ct * 32 + cl;
  const float a2 = A2[c * 16 + n];
  const size_t base = ((size_t)b << 10) + seg * 64;
  __shared__ __attribute__((aligned(16))) float sd[2][32][20];
  __shared__ __attribute__((aligned(16))) float sdu[2][32][20];
  __shared__ __attribute__((aligned(16))) float sB[2][32][20];
  const int li = tid >> 5, lj = tid & 31;   // 16 rows x 32 cols
  unsigned short rd, ru; float rb;
  auto issue = [&](int s0) {
    size_t rowi = base + s0 + li;
    rd = del[rowi * 384 + ct * 32 + lj];
    ru = uu [rowi * 384 + ct * 32 + lj];
    rb = bc [rowi * 32 + lj];
  };
  auto commit = [&](int buf) {
    float dd = bf2f(rd), uv = bf2f(ru);
    sd[buf][lj][li] = dd; sdu[buf][lj][li] = dd * uv; sB[buf][lj][li] = rb;
  };
  issue(0); commit(0);
  float h = 0.f, P = 1.f;
  for (int ch = 0; ch < 4; ++ch) {
    const int cur = ch & 1;
    if (ch + 1 < 4) issue((ch + 1) * 16);
    __syncthreads();
    f32x4 dv[4], duv[4], bmv[4];
    #pragma unroll
    for (int r = 0; r < 4; ++r) {
      dv[r]  = *(const f32x4*)&sd[cur][cl][r * 4];
      duv[r] = *(const f32x4*)&sdu[cur][cl][r * 4];
      bmv[r] = *(const f32x4*)&sB[cur][n][r * 4];
    }
    #pragma unroll
    for (int i = 0; i < 16; ++i) {
      float dA = __builtin_amdgcn_exp2f(dv[i >> 2][i & 3] * a2);
      h = fmaf(dA, h, duv[i >> 2][i & 3] * bmv[i >> 2][i & 3]);
      P *= dA;
    }
    if (ch + 1 < 4) { __syncthreads(); commit(cur ^ 1); }
  }
  size_t o = (size_t)((dir * 8 + b) * 16 + seg) * 6144 + c * 16 + n;
  Pseg[o] = P; Hseg[o] = h;
}

// ---------------- combine: h_in per segment (serial over 16 segs) ---------
__global__ __launch_bounds__(256) void scomb_k(
    const float* __restrict__ Pseg, const float* __restrict__ Hseg,
    float* __restrict__ Hin) {
  const int db = blockIdx.y;                   // dir*8+b
  const int r = blockIdx.x * 256 + threadIdx.x;  // c*16+n
  float h = 0.f;
  #pragma unroll
  for (int s = 0; s < 16; ++s) {
    size_t o = (size_t)(db * 16 + s) * 6144 + r;
    Hin[o] = h;
    h = Pseg[o] * h + Hseg[o];
  }
}

// ---------------- scan pass 2: full scan per segment, seeded --------------
__global__ __launch_bounds__(512) void scan2_k(
    const unsigned short* __restrict__ de0, const unsigned short* __restrict__ de1,
    const unsigned short* __restrict__ ub0, const unsigned short* __restrict__ ub1,
    const float* __restrict__ bc0, const float* __restrict__ bc1,
    const unsigned short* __restrict__ xz, const float* __restrict__ A2,
    const float* __restrict__ Dp, const float* __restrict__ Hin,
    unsigned short* __restrict__ Sb0, unsigned short* __restrict__ Sb1) {
  const int ct = blockIdx.x, b = blockIdx.y;
  const int dir = blockIdx.z >> 4, seg = blockIdx.z & 15;
  const unsigned short* del = dir ? de1 : de0;
  const unsigned short* uu  = dir ? ub1 : ub0;
  const float* bc  = dir ? bc1 : bc0;
  unsigned short* S = dir ? Sb1 : Sb0;
  const int tid = threadIdx.x;
  const int lane = tid & 63, wave = tid >> 6;
  const int n = lane & 15, cg = lane >> 4;
  const int cl = wave * 4 + cg;          // local channel 0..31
  const int c = ct * 32 + cl;
  const float a2 = A2[c * 16 + n];
  const float dpc = Dp[c];
  const size_t base = (size_t)b << 10;
  const int segoff = seg * 64;
  __shared__ __attribute__((aligned(16))) float sd[2][32][20];
  __shared__ __attribute__((aligned(16))) float sdu[2][32][20];
  __shared__ __attribute__((aligned(16))) float su[2][32][20];
  __shared__ __attribute__((aligned(16))) float sz[2][32][20];
  __shared__ __attribute__((aligned(16))) float sbc[2][32][20];
  const int li = tid >> 5, lj = tid & 31;
  unsigned short rd, ru, rz; float rb;
  auto issue = [&](int s0) {
    size_t rowi = base + segoff + s0 + li;
    rd = del[rowi * 384 + ct * 32 + lj];
    ru = uu [rowi * 384 + ct * 32 + lj];
    int t = dir ? (1023 - (segoff + s0 + li)) : (segoff + s0 + li);
    rz = xz[(base + t) * 768 + 384 + ct * 32 + lj];
    rb = bc[rowi * 32 + lj];
  };
  auto commit = [&](int buf) {
    float dd = bf2f(rd), uv = bf2f(ru);
    sd[buf][lj][li] = dd; sdu[buf][lj][li] = dd * uv;
    su[buf][lj][li] = uv; sz[buf][lj][li] = bf2f(rz);
    sbc[buf][lj][li] = rb;
  };
  issue(0); commit(0);
  float h = Hin[(size_t)((dir * 8 + b) * 16 + seg) * 6144 + c * 16 + n];
  for (int ch = 0; ch < 4; ++ch) {
    const int cur = ch & 1;
    if (ch + 1 < 4) issue((ch + 1) * 16);
    __syncthreads();
    f32x4 dv[4], duv[4], bmv[4], cmv[4];
    #pragma unroll
    for (int r = 0; r < 4; ++r) {
      dv[r]  = *(const f32x4*)&sd[cur][cl][r * 4];
      duv[r] = *(const f32x4*)&sdu[cur][cl][r * 4];
      bmv[r] = *(const f32x4*)&sbc[cur][n][r * 4];
      cmv[r] = *(const f32x4*)&sbc[cur][16 + n][r * 4];
    }
    float p[16];
    #pragma unroll
    for (int i = 0; i < 16; ++i) {
      float dA = __builtin_amdgcn_exp2f(dv[i >> 2][i & 3] * a2);
      h = fmaf(dA, h, duv[i >> 2][i & 3] * bmv[i >> 2][i & 3]);
      p[i] = h * cmv[i >> 2][i & 3];
    }
    float q8[8];
    #pragma unroll
    for (int j = 0; j < 8; ++j) {
      float send = (n & 8) ? p[j] : p[j + 8];
      float recv = __shfl_xor(send, 8);
      float keep = (n & 8) ? p[j + 8] : p[j];
      q8[j] = keep + recv;
    }
    float q4[4];
    #pragma unroll
    for (int j = 0; j < 4; ++j) {
      float send = (n & 4) ? q8[j] : q8[j + 4];
      float recv = __shfl_xor(send, 4);
      float keep = (n & 4) ? q8[j + 4] : q8[j];
      q4[j] = keep + recv;
    }
    float q2[2];
    #pragma unroll
    for (int j = 0; j < 2; ++j) {
      float send = (n & 2) ? q4[j] : q4[j + 2];
      float recv = __shfl_xor(send, 2);
      float keep = (n & 2) ? q4[j + 2] : q4[j];
      q2[j] = keep + recv;
    }
    float send = (n & 1) ? q2[0] : q2[1];
    float recv = __shfl_xor(send, 1);
    float keep = (n & 1) ? q2[1] : q2[0];
    float ysum = keep + recv;
    float uvn = su[cur][cl][n];
    float zz  = sz[cur][cl][n];
    float sig = __builtin_amdgcn_rcpf(1.f + __builtin_amdgcn_exp2f(-zz * L2E));
    float y = (ysum + uvn * dpc) * (zz * sig);
    int s = segoff + ch * 16 + n;
    int t = dir ? (1023 - s) : s;
    S[(base + t) * 384 + c] = f2bf(y);
    if (ch + 1 < 4) { __syncthreads(); commit(cur ^ 1); }
  }
}

// ---------------- final: dwconv3x3 gate + transpose + residual ------------
// phase 1: thread = (1 l) x (8 ch octet), bf16x8 taps; phase 2: NCHW out.
__global__ __launch_bounds__(256) void final_k(
    const float* __restrict__ G, const unsigned short* __restrict__ xb,
    const float* __restrict__ nf, const float* __restrict__ nw,
    const float* __restrict__ x, const float* __restrict__ dww,
    const float* __restrict__ dwb, const float* __restrict__ rs,
    float* __restrict__ out) {
  __shared__ float tile[64][33];
  __shared__ float wq[9][64];     // dww * nw, [tap][c]
  __shared__ float bbs[64], nws[64];
  const int l0 = blockIdx.x * 32, c0 = blockIdx.y * 64, b = blockIdx.z;
  const int tid = threadIdx.x;
  for (int i = tid; i < 576; i += 256) {
    int c = i / 9, q = i - c * 9;
    wq[q][c] = dww[(size_t)(c0 + c) * 9 + q] * nw[c0 + c];
  }
  if (tid < 64) { bbs[tid] = dwb[c0 + tid]; nws[tid] = nw[c0 + tid]; }
  __syncthreads();
  {
    const int oct = tid & 7, li = tid >> 3;     // 8 octets x 32 l
    const int l = l0 + li;
    const int hh = l >> 5, ww = l & 31;
    float acc[8];
    {
      f32x4 ba = *(const f32x4*)&bbs[oct * 8];
      f32x4 bb2 = *(const f32x4*)&bbs[oct * 8 + 4];
      #pragma unroll
      for (int j = 0; j < 4; ++j) { acc[j] = ba[j]; acc[j + 4] = bb2[j]; }
    }
    #pragma unroll
    for (int di = -1; di <= 1; ++di) {
      int h2 = hh + di;
      if (h2 < 0 || h2 > 31) continue;
      #pragma unroll
      for (int dj = -1; dj <= 1; ++dj) {
        int w2 = ww + dj;
        if (w2 < 0 || w2 > 31) continue;
        int lp = h2 * 32 + w2;
        float nfl = nf[(b << 10) + lp];
        u16x8 v = *(const u16x8*)&xb[(size_t)((b << 10) + lp) * 384 + c0 + oct * 8];
        int q = (di + 1) * 3 + (dj + 1);
        f32x4 wa = *(const f32x4*)&wq[q][oct * 8];
        f32x4 wb = *(const f32x4*)&wq[q][oct * 8 + 4];
        #pragma unroll
        for (int j = 0; j < 4; ++j) {
          acc[j]     = fmaf(bf2f(v[j]) * nfl, wa[j], acc[j]);
          acc[j + 4] = fmaf(bf2f(v[j + 4]) * nfl, wb[j], acc[j + 4]);
        }
      }
    }
    size_t ri = (size_t)((b << 10) + l) * 384 + c0 + oct * 8;
    float nfl0 = nf[(b << 10) + l];
    u16x8 xc = *(const u16x8*)&xb[ri];
    f32x4 g0 = *(const f32x4*)&G[ri];
    f32x4 g1 = *(const f32x4*)&G[ri + 4];
    #pragma unroll
    for (int j = 0; j < 8; ++j) {
      float xv = bf2f(xc[j]) * nfl0 * nws[oct * 8 + j];
      float sig = __builtin_amdgcn_rcpf(1.f + __builtin_amdgcn_exp2f(-acc[j] * L2E));
      float gg = (j < 4) ? g0[j] : g1[j - 4];
      tile[oct * 8 + j][li] = gg + xv * sig;
    }
  }
  __syncthreads();
  {
    const int lw = tid & 31, cr = tid >> 5;
    const float rsv = rs[0];
    for (int p = 0; p < 8; ++p) {
      int c = c0 + p * 8 + cr;
      size_t o = ((size_t)(b * 384 + c) << 10) + l0 + lw;
      out[o] = x[o] + rsv * tile[p * 8 + cr][lw];
    }
  }
}

// ---------------- host ----------------------------------------------------
extern "C" void kernel_launch(void* const* d_in, const int* in_sizes, int n_in,
                              void* d_out, int out_size, void* d_ws, size_t ws_size,
                              hipStream_t stream) {
  const float* x         = (const float*)d_in[0];
  const float* norm_w    = (const float*)d_in[1];
  const float* in_proj_w = (const float*)d_in[2];
  const float* conv1d_w  = (const float*)d_in[3];
  const float* conv1d_b  = (const float*)d_in[4];
  const float* x_proj_w  = (const float*)d_in[5];
  const float* dt_proj_w = (const float*)d_in[6];
  const float* dt_proj_b = (const float*)d_in[7];
  const float* A_log     = (const float*)d_in[8];
  const float* D_param   = (const float*)d_in[9];
  const float* out_proj_w= (const float*)d_in[10];
  const float* scale_mod = (const float*)d_in[11];
  const float* dw_w      = (const float*)d_in[12];
  const float* dw_b      = (const float*)d_in[13];
  const float* res_scale = (const float*)d_in[14];
  float* out = (float*)d_out;

  char* base = (char*)d_ws;
  size_t off = 0;
  auto alloc = [&](size_t bytes) {
    off = (off + 255) & ~(size_t)255;
    void* p = base + off;
    off += bytes;
    return p;
  };
  const size_t B_BLC = (size_t)8192 * 384 * 2;   // 6.29 MB bf16

  unsigned short* xb   = (unsigned short*)alloc(B_BLC);
  float*          nf   = (float*)alloc((size_t)8192 * 4);
  unsigned short* xz   = (unsigned short*)alloc((size_t)8192 * 768 * 2);
  unsigned short* u_b0 = (unsigned short*)alloc(B_BLC);
  unsigned short* u_b1 = (unsigned short*)alloc(B_BLC);
  unsigned short* dtp0 = (unsigned short*)alloc((size_t)8192 * 32 * 2);
  unsigned short* dtp1 = (unsigned short*)alloc((size_t)8192 * 32 * 2);
  float*          bc0  = (float*)alloc((size_t)8192 * 32 * 4);
  float*          bc1  = (float*)alloc((size_t)8192 * 32 * 4);
  unsigned short* de0  = (unsigned short*)alloc(B_BLC);
  unsigned short* de1  = (unsigned short*)alloc(B_BLC);
  unsigned short* Sb0  = (unsigned short*)alloc(B_BLC);
  unsigned short* Sb1  = (unsigned short*)alloc(B_BLC);
  float*          Pseg = (float*)alloc((size_t)1572864 * 4);
  float*          Hseg = (float*)alloc((size_t)1572864 * 4);
  float*          Hin  = (float*)alloc((size_t)1572864 * 4);
  unsigned short* W_in = (unsigned short*)alloc((size_t)768 * 384 * 2);
  unsigned short* W_x  = (unsigned short*)alloc((size_t)64 * 384 * 2);
  unsigned short* W_dt = (unsigned short*)alloc((size_t)384 * 32 * 2);
  unsigned short* W_out= (unsigned short*)alloc((size_t)384 * 384 * 2);
  float*          A2   = (float*)alloc((size_t)384 * 16 * 4);
  float*          G    = (float*)alloc((size_t)8192 * 384 * 4);

  prep_k<<<dim3(1152, 5), 256, 0, stream>>>(in_proj_w, x_proj_w, dt_proj_w,
                                            out_proj_w, A_log, norm_w,
                                            W_in, W_x, W_dt, W_out, A2);
  transpose_k<<<dim3(32, 8), 256, 0, stream>>>(x, xb, nf);
  gemm_k<0, 0><<<dim3(12, 128), 256, 0, stream>>>(xb, xb, W_in, 384, 768,
                                                  nullptr, nullptr, xz, xz, nf);
  conv_silu_k<<<dim3(128, 8, 2), 384, 0, stream>>>(xz, conv1d_w, conv1d_b,
                                                   u_b0, u_b1);
  gemm_k<1, 0><<<dim3(1, 128, 2), 256, 0, stream>>>(u_b0, u_b1, W_x, 384, 64,
                                                    bc0, bc1, dtp0, dtp1, nullptr);
  gemm_k<2, 0><<<dim3(6, 128, 2), 256, 0, stream>>>(dtp0, dtp1, W_dt, 32, 384,
                                                    nullptr, nullptr, de0, de1,
                                                    dt_proj_b);
  scan1_k<<<dim3(12, 8, 32), 512, 0, stream>>>(de0, de1, u_b0, u_b1, bc0, bc1,
                                               A2, Pseg, Hseg);
  scomb_k<<<dim3(24, 16), 256, 0, stream>>>(Pseg, Hseg, Hin);
  scan2_k<<<dim3(12, 8, 32), 512, 0, stream>>>(de0, de1, u_b0, u_b1, bc0, bc1,
                                               xz, A2, D_param, Hin, Sb0, Sb1);
  gemm_k<3, 1><<<dim3(6, 128), 256, 0, stream>>>(Sb0, Sb1, W_out, 384, 384,
                                                 G, G, nullptr, nullptr,
                                                 scale_mod);
  final_k<<<dim3(32, 6, 8), 256, 0, stream>>>(G, xb, nf, norm_w, x, dw_w, dw_b,
                                              res_scale, out);
}

// Round 6
// 247.347 us; speedup vs baseline: 2.3468x; 1.0421x over previous
//
#include <hip/hip_runtime.h>
#include <hip/hip_bf16.h>

// HiMambaBottleneck: B=8, C=384, H=W=32, L=1024, BL=8192, dt_rank=24, N=16.
//  - bf16 mid-pipeline; rmsnorm folded into W_in + in_proj epilogue.
//  - scan: 2-pass segmented 16x64; prefetch-all + single-barrier blocks;
//    combine merged into scan2 (PH prefix replay).
//  - in/out_proj: 128^2 tile + global_load_lds (m97 structure).

typedef __attribute__((ext_vector_type(8))) short bf16x8;
typedef __attribute__((ext_vector_type(8))) unsigned short u16x8;
typedef __attribute__((ext_vector_type(4))) float f32x4;

#define L2E 1.44269504088896340736f

static __device__ __forceinline__ unsigned short f2bf(float f) {
  unsigned int u = __builtin_bit_cast(unsigned int, f);
  u += 0x7fff + ((u >> 16) & 1);  // RNE
  return (unsigned short)(u >> 16);
}
static __device__ __forceinline__ float bf2f(unsigned short u) {
  unsigned int v = (unsigned int)u << 16;
  return __builtin_bit_cast(float, v);
}

#define GLOAD_LDS16(g, l)                                             \
  __builtin_amdgcn_global_load_lds(                                   \
      (const __attribute__((address_space(1))) unsigned int*)(g),     \
      (__attribute__((address_space(3))) unsigned int*)(l), 16, 0, 0)

// ---------------- prep: weights -> bf16 (padded), A2 table ----------------
__global__ __launch_bounds__(256) void prep_k(
    const float* __restrict__ in_w, const float* __restrict__ x_w,
    const float* __restrict__ dt_w, const float* __restrict__ out_w,
    const float* __restrict__ A_log, const float* __restrict__ nw,
    unsigned short* __restrict__ W_in, unsigned short* __restrict__ W_x,
    unsigned short* __restrict__ W_dt, unsigned short* __restrict__ W_out,
    float* __restrict__ A2) {
  int idx = blockIdx.x * 256 + threadIdx.x;
  switch (blockIdx.y) {
    case 0: if (idx < 768 * 384) W_in[idx] = f2bf(in_w[idx] * nw[idx % 384]); break;
    case 1: if (idx < 64 * 384) { int n = idx / 384, k = idx - n * 384;
              W_x[idx] = f2bf(n < 56 ? x_w[n * 384 + k] : 0.f); } break;
    case 2: if (idx < 384 * 32) { int n = idx >> 5, k = idx & 31;
              W_dt[idx] = f2bf(k < 24 ? dt_w[n * 24 + k] : 0.f); } break;
    case 3: if (idx < 384 * 384) W_out[idx] = f2bf(out_w[idx]); break;
    case 4: if (idx < 384 * 16) A2[idx] = -expf(A_log[idx]) * L2E; break;
  }
}

// ---------------- transpose-lite: x NCHW -> xb (CL bf16) + nf[bl] ---------
__global__ __launch_bounds__(256) void transpose_k(
    const float* __restrict__ x, unsigned short* __restrict__ xb,
    float* __restrict__ nf) {
  const int b = blockIdx.y;
  const int l0 = blockIdx.x * 32;
  const int tid = threadIdx.x;
  const int cr = tid >> 5, lw = tid & 31;
  const int cj = tid & 63, lr = tid >> 6;
  __shared__ float t64[64][33];
  __shared__ float part[8][33];
  float acc = 0.f;
  for (int cc = 0; cc < 6; ++cc) {
    #pragma unroll
    for (int k = 0; k < 8; ++k) {
      int cp = k * 8 + cr;
      int c = cc * 64 + cp;
      float v = x[(((size_t)(b * 384 + c)) << 10) + l0 + lw];
      t64[cp][lw] = v;
      acc = fmaf(v, v, acc);
    }
    __syncthreads();
    #pragma unroll
    for (int k2 = 0; k2 < 8; ++k2) {
      int ll = lr + 4 * k2;
      xb[((size_t)((b << 10) + l0 + ll)) * 384 + cc * 64 + cj] = f2bf(t64[cj][ll]);
    }
    __syncthreads();
  }
  part[cr][lw] = acc;
  __syncthreads();
  if (tid < 32) {
    float s = part[0][tid] + part[1][tid] + part[2][tid] + part[3][tid] +
              part[4][tid] + part[5][tid] + part[6][tid] + part[7][tid];
    nf[(b << 10) + l0 + tid] = rsqrtf(s * (1.f / 384.f) + 1e-6f);
  }
}

// ---------------- 128^2 MFMA GEMM (m97 structure) -------------------------
// EPI 0: in_proj (bf16 out x nf[m], gload_lds); EPI 3: out_proj (f32 x scale,
// SUMIN: reg-staged A = S0+S1).
template <int EPI, int SUMIN>
__global__ __launch_bounds__(256) void gemm128_k(
    const unsigned short* __restrict__ A0u, const unsigned short* __restrict__ A1u,
    const unsigned short* __restrict__ Bw, int K, int N,
    float* __restrict__ outf, unsigned short* __restrict__ outb,
    const float* __restrict__ aux) {
  __shared__ __attribute__((aligned(16))) unsigned short As[128 * 32];
  __shared__ __attribute__((aligned(16))) unsigned short Bs[128 * 32];
  const int n0 = blockIdx.x * 128, m0 = blockIdx.y * 128;
  const int tid = threadIdx.x;
  const int lane = tid & 63, wave = tid >> 6;
  const int wm = wave >> 1, wn = wave & 1;
  const int fr = lane & 15, ks = (lane >> 4) * 8;
  const int row = tid >> 2, colseg = (tid & 3) * 8;
  const unsigned short* pA0 = A0u + (size_t)(m0 + row) * K + colseg;
  const unsigned short* pA1 = A0u + (size_t)(m0 + 64 + row) * K + colseg;
  const unsigned short* pB0 = Bw + (size_t)(n0 + row) * K + colseg;
  const unsigned short* pB1 = Bw + (size_t)(n0 + 64 + row) * K + colseg;
  unsigned short* lA0 = As + wave * 512;
  unsigned short* lA1 = As + 2048 + wave * 512;
  unsigned short* lB0 = Bs + wave * 512;
  unsigned short* lB1 = Bs + 2048 + wave * 512;
  f32x4 acc[4][4] = {};
  for (int k0 = 0; k0 < K; k0 += 32) {
    __syncthreads();
    if (SUMIN) {
      #pragma unroll
      for (int p = 0; p < 2; ++p) {
        int r = p * 64 + row;
        u16x8 va = *(const u16x8*)&A0u[(size_t)(m0 + r) * K + k0 + colseg];
        u16x8 vb = *(const u16x8*)&A1u[(size_t)(m0 + r) * K + k0 + colseg];
        u16x8 s;
        #pragma unroll
        for (int j = 0; j < 8; ++j) s[j] = f2bf(bf2f(va[j]) + bf2f(vb[j]));
        *(u16x8*)&As[r * 32 + colseg] = s;
      }
    } else {
      GLOAD_LDS16(pA0, lA0);
      GLOAD_LDS16(pA1, lA1);
      pA0 += 32; pA1 += 32;
    }
    GLOAD_LDS16(pB0, lB0);
    GLOAD_LDS16(pB1, lB1);
    pB0 += 32; pB1 += 32;
    __syncthreads();
    bf16x8 af[4], bf[4];
    #pragma unroll
    for (int mi = 0; mi < 4; ++mi)
      af[mi] = *(const bf16x8*)&As[(wm * 64 + mi * 16 + fr) * 32 + ks];
    #pragma unroll
    for (int ni = 0; ni < 4; ++ni)
      bf[ni] = *(const bf16x8*)&Bs[(wn * 64 + ni * 16 + fr) * 32 + ks];
    #pragma unroll
    for (int mi = 0; mi < 4; ++mi)
      #pragma unroll
      for (int ni = 0; ni < 4; ++ni)
        acc[mi][ni] = __builtin_amdgcn_mfma_f32_16x16x32_bf16(af[mi], bf[ni], acc[mi][ni], 0, 0, 0);
  }
  #pragma unroll
  for (int mi = 0; mi < 4; ++mi)
    #pragma unroll
    for (int ni = 0; ni < 4; ++ni)
      #pragma unroll
      for (int j = 0; j < 4; ++j) {
        int m = m0 + wm * 64 + mi * 16 + (lane >> 4) * 4 + j;
        int n = n0 + wn * 64 + ni * 16 + fr;
        float v = acc[mi][ni][j];
        if (EPI == 0) {
          outb[(size_t)m * N + n] = f2bf(v * aux[m]);   // x nf[m] -> xz bf16
        } else {
          outf[(size_t)m * N + n] = v * aux[0];         // x scale -> G f32
        }
      }
}

// ---------------- small GEMM 64^2: EPI1 x_proj, EPI2 dt_proj --------------
template <int EPI>
__global__ __launch_bounds__(256) void gemm_k(
    const unsigned short* __restrict__ A0u, const unsigned short* __restrict__ A1u,
    const unsigned short* __restrict__ Bw, int K, int N,
    float* __restrict__ of0, float* __restrict__ of1,
    unsigned short* __restrict__ ob0, unsigned short* __restrict__ ob1,
    const float* __restrict__ aux) {
  const unsigned short* A = blockIdx.z ? A1u : A0u;
  float* outf = blockIdx.z ? of1 : of0;
  unsigned short* outb = blockIdx.z ? ob1 : ob0;
  __shared__ unsigned short As[64][40];
  __shared__ unsigned short Bs[64][40];
  const int n0 = blockIdx.x * 64, m0 = blockIdx.y * 64;
  const int tid = threadIdx.x;
  const int lane = tid & 63, wave = tid >> 6;
  const int wm = wave >> 1, wn = wave & 1;
  const int lrow = tid >> 2, lseg = (tid & 3) * 8;
  const int fr = lane & 15, ks = (lane >> 4) * 8;
  f32x4 acc[2][2] = {};
  for (int k0 = 0; k0 < K; k0 += 32) {
    __syncthreads();
    *(bf16x8*)&As[lrow][lseg] = *(const bf16x8*)&A[(size_t)(m0 + lrow) * K + k0 + lseg];
    *(bf16x8*)&Bs[lrow][lseg] = *(const bf16x8*)&Bw[(size_t)(n0 + lrow) * K + k0 + lseg];
    __syncthreads();
    bf16x8 a0 = *(const bf16x8*)&As[wm * 32 + fr][ks];
    bf16x8 a1 = *(const bf16x8*)&As[wm * 32 + 16 + fr][ks];
    bf16x8 b0 = *(const bf16x8*)&Bs[wn * 32 + fr][ks];
    bf16x8 b1 = *(const bf16x8*)&Bs[wn * 32 + 16 + fr][ks];
    acc[0][0] = __builtin_amdgcn_mfma_f32_16x16x32_bf16(a0, b0, acc[0][0], 0, 0, 0);
    acc[0][1] = __builtin_amdgcn_mfma_f32_16x16x32_bf16(a0, b1, acc[0][1], 0, 0, 0);
    acc[1][0] = __builtin_amdgcn_mfma_f32_16x16x32_bf16(a1, b0, acc[1][0], 0, 0, 0);
    acc[1][1] = __builtin_amdgcn_mfma_f32_16x16x32_bf16(a1, b1, acc[1][1], 0, 0, 0);
  }
  #pragma unroll
  for (int mi = 0; mi < 2; ++mi)
    #pragma unroll
    for (int ni = 0; ni < 2; ++ni)
      #pragma unroll
      for (int j = 0; j < 4; ++j) {
        int m = m0 + wm * 32 + mi * 16 + (lane >> 4) * 4 + j;
        int n = n0 + wn * 32 + ni * 16 + (lane & 15);
        float v = acc[mi][ni][j];
        if (EPI == 1) {
          if (n < 24) outb[m * 32 + n] = f2bf(v);
          else if (n < 32) outb[m * 32 + n] = 0;
          if (n >= 24 && n < 56) outf[m * 32 + (n - 24)] = v;
        } else {
          float t = v + aux[n];
          float sp = (t > 20.f) ? t : log1pf(expf(t));
          outb[(size_t)m * N + n] = f2bf(sp);
        }
      }
}

// ---------------- causal depthwise conv1d + silu (both directions) --------
__global__ __launch_bounds__(384) void conv_silu_k(
    const unsigned short* __restrict__ xz, const float* __restrict__ cw,
    const float* __restrict__ cb,
    unsigned short* __restrict__ ub0, unsigned short* __restrict__ ub1) {
  const int st = blockIdx.x, b = blockIdx.y, dir = blockIdx.z;
  const int c = threadIdx.x;
  const int s0 = st * 8;
  const float w0 = cw[c * 4 + 0], w1 = cw[c * 4 + 1];
  const float w2 = cw[c * 4 + 2], w3 = cw[c * 4 + 3];
  const float bb = cb[c];
  unsigned short* ub = dir ? ub1 : ub0;
  float xv[11];
  #pragma unroll
  for (int k = 0; k < 11; ++k) {
    int j = s0 - 3 + k;
    float v = 0.f;
    if (j >= 0) {
      int t = dir ? (1023 - j) : j;
      v = bf2f(xz[(size_t)((b << 10) + t) * 768 + c]);
    }
    xv[k] = v;
  }
  #pragma unroll
  for (int s = 0; s < 8; ++s) {
    float a = bb + xv[s] * w0 + xv[s + 1] * w1 + xv[s + 2] * w2 + xv[s + 3] * w3;
    float uv = a * __builtin_amdgcn_rcpf(1.f + __builtin_amdgcn_exp2f(-a * L2E));
    ub[(size_t)((b << 10) + s0 + s) * 384 + c] = f2bf(uv);
  }
}

// ---------------- scan pass 1: per-segment (P, h) -> PH interleaved -------
// grid (12 ct, 8 b, 32 = dir*16+seg); 512 thr; prefetch-all, 1 barrier.
__global__ __launch_bounds__(512) void scan1_k(
    const unsigned short* __restrict__ de0, const unsigned short* __restrict__ de1,
    const unsigned short* __restrict__ ub0, const unsigned short* __restrict__ ub1,
    const float* __restrict__ bc0, const float* __restrict__ bc1,
    const float* __restrict__ A2, float* __restrict__ PH) {
  const int ct = blockIdx.x, b = blockIdx.y;
  const int dir = blockIdx.z >> 4, seg = blockIdx.z & 15;
  const unsigned short* del = dir ? de1 : de0;
  const unsigned short* uu  = dir ? ub1 : ub0;
  const float* bc  = dir ? bc1 : bc0;
  const int tid = threadIdx.x;
  const int lane = tid & 63, wave = tid >> 6;
  const int n = lane & 15, cg = lane >> 4;
  const int cl = wave * 4 + cg;
  const int c = ct * 32 + cl;
  const float a2 = A2[c * 16 + n];
  const size_t base = ((size_t)b << 10) + seg * 64;
  __shared__ __attribute__((aligned(16))) float sd[32][68];
  __shared__ __attribute__((aligned(16))) float su[32][68];
  __shared__ __attribute__((aligned(16))) float sB[16][68];
  const int li = tid >> 5, lj = tid & 31;
  const int li3 = tid >> 4, lj3 = tid & 15;
  unsigned short rd[4], ru[4];
  float rb[2];
  #pragma unroll
  for (int k = 0; k < 4; ++k) {
    size_t rowi = base + k * 16 + li;
    rd[k] = del[rowi * 384 + ct * 32 + lj];
    ru[k] = uu [rowi * 384 + ct * 32 + lj];
  }
  #pragma unroll
  for (int k = 0; k < 2; ++k)
    rb[k] = bc[(base + k * 32 + li3) * 32 + lj3];
  #pragma unroll
  for (int k = 0; k < 4; ++k) {
    sd[lj][k * 16 + li] = bf2f(rd[k]);
    su[lj][k * 16 + li] = bf2f(ru[k]);
  }
  #pragma unroll
  for (int k = 0; k < 2; ++k) sB[lj3][k * 32 + li3] = rb[k];
  __syncthreads();
  float h = 0.f, P = 1.f;
  for (int ch = 0; ch < 4; ++ch) {
    f32x4 dv[4], uv4[4], bmv[4];
    #pragma unroll
    for (int r = 0; r < 4; ++r) {
      dv[r]  = *(const f32x4*)&sd[cl][ch * 16 + r * 4];
      uv4[r] = *(const f32x4*)&su[cl][ch * 16 + r * 4];
      bmv[r] = *(const f32x4*)&sB[n][ch * 16 + r * 4];
    }
    #pragma unroll
    for (int i = 0; i < 16; ++i) {
      float dd = dv[i >> 2][i & 3];
      float dA = __builtin_amdgcn_exp2f(dd * a2);
      h = fmaf(dA, h, dd * uv4[i >> 2][i & 3] * bmv[i >> 2][i & 3]);
      P *= dA;
    }
  }
  size_t o = (size_t)((dir * 8 + b) * 16 + seg) * 6144 + c * 16 + n;
  *(float2*)&PH[o * 2] = make_float2(P, h);
}

// ---------------- scan pass 2: seeded full scan + gate (combine merged) ---
__global__ __launch_bounds__(512) void scan2_k(
    const unsigned short* __restrict__ de0, const unsigned short* __restrict__ de1,
    const unsigned short* __restrict__ ub0, const unsigned short* __restrict__ ub1,
    const float* __restrict__ bc0, const float* __restrict__ bc1,
    const unsigned short* __restrict__ xz, const float* __restrict__ A2,
    const float* __restrict__ Dp, const float* __restrict__ PH,
    unsigned short* __restrict__ Sb0, unsigned short* __restrict__ Sb1) {
  const int ct = blockIdx.x, b = blockIdx.y;
  const int dir = blockIdx.z >> 4, seg = blockIdx.z & 15;
  const unsigned short* del = dir ? de1 : de0;
  const unsigned short* uu  = dir ? ub1 : ub0;
  const float* bc  = dir ? bc1 : bc0;
  unsigned short* S = dir ? Sb1 : Sb0;
  const int tid = threadIdx.x;
  const int lane = tid & 63, wave = tid >> 6;
  const int n = lane & 15, cg = lane >> 4;
  const int cl = wave * 4 + cg;
  const int c = ct * 32 + cl;
  const float a2 = A2[c * 16 + n];
  const float dpc = Dp[c];
  const size_t base = (size_t)b << 10;
  const int segoff = seg * 64;
  __shared__ __attribute__((aligned(16))) float sd[32][68];
  __shared__ __attribute__((aligned(16))) float su[32][68];
  __shared__ __attribute__((aligned(16))) float sz[32][68];
  __shared__ __attribute__((aligned(16))) float sbc[32][68];
  const int li = tid >> 5, lj = tid & 31;
  unsigned short rd[4], ru[4], rz[4];
  float rb[4];
  #pragma unroll
  for (int k = 0; k < 4; ++k) {
    size_t rowi = base + segoff + k * 16 + li;
    rd[k] = del[rowi * 384 + ct * 32 + lj];
    ru[k] = uu [rowi * 384 + ct * 32 + lj];
    int t = dir ? (1023 - (segoff + k * 16 + li)) : (segoff + k * 16 + li);
    rz[k] = xz[(base + t) * 768 + 384 + ct * 32 + lj];
    rb[k] = bc[rowi * 32 + lj];
  }
  // prefix combine: h_in from PH (loads independent, chain is fma-only)
  float h = 0.f;
  {
    size_t rb2 = ((size_t)((dir * 8 + b) * 16) * 6144 + c * 16 + n) * 2;
    #pragma unroll
    for (int s = 0; s < 15; ++s) {
      float2 ph = *(const float2*)&PH[rb2 + (size_t)s * 12288];
      h = (s < seg) ? fmaf(ph.x, h, ph.y) : h;
    }
  }
  #pragma unroll
  for (int k = 0; k < 4; ++k) {
    sd[lj][k * 16 + li] = bf2f(rd[k]);
    su[lj][k * 16 + li] = bf2f(ru[k]);
    sz[lj][k * 16 + li] = bf2f(rz[k]);
    sbc[lj][k * 16 + li] = rb[k];
  }
  __syncthreads();
  for (int ch = 0; ch < 4; ++ch) {
    f32x4 dv[4], uv4[4], bmv[4], cmv[4];
    #pragma unroll
    for (int r = 0; r < 4; ++r) {
      dv[r]  = *(const f32x4*)&sd[cl][ch * 16 + r * 4];
      uv4[r] = *(const f32x4*)&su[cl][ch * 16 + r * 4];
      bmv[r] = *(const f32x4*)&sbc[n][ch * 16 + r * 4];
      cmv[r] = *(const f32x4*)&sbc[16 + n][ch * 16 + r * 4];
    }
    float p[16];
    #pragma unroll
    for (int i = 0; i < 16; ++i) {
      float dd = dv[i >> 2][i & 3];
      float dA = __builtin_amdgcn_exp2f(dd * a2);
      h = fmaf(dA, h, dd * uv4[i >> 2][i & 3] * bmv[i >> 2][i & 3]);
      p[i] = h * cmv[i >> 2][i & 3];
    }
    float q8[8];
    #pragma unroll
    for (int j = 0; j < 8; ++j) {
      float send = (n & 8) ? p[j] : p[j + 8];
      float recv = __shfl_xor(send, 8);
      float keep = (n & 8) ? p[j + 8] : p[j];
      q8[j] = keep + recv;
    }
    float q4[4];
    #pragma unroll
    for (int j = 0; j < 4; ++j) {
      float send = (n & 4) ? q8[j] : q8[j + 4];
      float recv = __shfl_xor(send, 4);
      float keep = (n & 4) ? q8[j + 4] : q8[j];
      q4[j] = keep + recv;
    }
    float q2[2];
    #pragma unroll
    for (int j = 0; j < 2; ++j) {
      float send = (n & 2) ? q4[j] : q4[j + 2];
      float recv = __shfl_xor(send, 2);
      float keep = (n & 2) ? q4[j + 2] : q4[j];
      q2[j] = keep + recv;
    }
    float send = (n & 1) ? q2[0] : q2[1];
    float recv = __shfl_xor(send, 1);
    float keep = (n & 1) ? q2[1] : q2[0];
    float ysum = keep + recv;
    float uvn = su[cl][ch * 16 + n];
    float zz  = sz[cl][ch * 16 + n];
    float sig = __builtin_amdgcn_rcpf(1.f + __builtin_amdgcn_exp2f(-zz * L2E));
    float y = (ysum + uvn * dpc) * (zz * sig);
    int s = segoff + ch * 16 + n;
    int t = dir ? (1023 - s) : s;
    S[(base + t) * 384 + c] = f2bf(y);
  }
}

// ---------------- final: dwconv3x3 gate + transpose + residual ------------
__global__ __launch_bounds__(256) void final_k(
    const float* __restrict__ G, const unsigned short* __restrict__ xb,
    const float* __restrict__ nf, const float* __restrict__ nw,
    const float* __restrict__ x, const float* __restrict__ dww,
    const float* __restrict__ dwb, const float* __restrict__ rs,
    float* __restrict__ out) {
  __shared__ float tile[64][33];
  __shared__ float wq[9][64];
  __shared__ float bbs[64], nws[64];
  const int l0 = blockIdx.x * 32, c0 = blockIdx.y * 64, b = blockIdx.z;
  const int tid = threadIdx.x;
  for (int i = tid; i < 576; i += 256) {
    int c = i / 9, q = i - c * 9;
    wq[q][c] = dww[(size_t)(c0 + c) * 9 + q] * nw[c0 + c];
  }
  if (tid < 64) { bbs[tid] = dwb[c0 + tid]; nws[tid] = nw[c0 + tid]; }
  __syncthreads();
  {
    const int oct = tid & 7, li = tid >> 3;
    const int l = l0 + li;
    const int hh = l >> 5, ww = l & 31;
    float acc[8];
    {
      f32x4 ba = *(const f32x4*)&bbs[oct * 8];
      f32x4 bb2 = *(const f32x4*)&bbs[oct * 8 + 4];
      #pragma unroll
      for (int j = 0; j < 4; ++j) { acc[j] = ba[j]; acc[j + 4] = bb2[j]; }
    }
    #pragma unroll
    for (int di = -1; di <= 1; ++di) {
      int h2 = hh + di;
      if (h2 < 0 || h2 > 31) continue;
      #pragma unroll
      for (int dj = -1; dj <= 1; ++dj) {
        int w2 = ww + dj;
        if (w2 < 0 || w2 > 31) continue;
        int lp = h2 * 32 + w2;
        float nfl = nf[(b << 10) + lp];
        u16x8 v = *(const u16x8*)&xb[(size_t)((b << 10) + lp) * 384 + c0 + oct * 8];
        int q = (di + 1) * 3 + (dj + 1);
        f32x4 wa = *(const f32x4*)&wq[q][oct * 8];
        f32x4 wb = *(const f32x4*)&wq[q][oct * 8 + 4];
        #pragma unroll
        for (int j = 0; j < 4; ++j) {
          acc[j]     = fmaf(bf2f(v[j]) * nfl, wa[j], acc[j]);
          acc[j + 4] = fmaf(bf2f(v[j + 4]) * nfl, wb[j], acc[j + 4]);
        }
      }
    }
    size_t ri = (size_t)((b << 10) + l) * 384 + c0 + oct * 8;
    float nfl0 = nf[(b << 10) + l];
    u16x8 xc = *(const u16x8*)&xb[ri];
    f32x4 g0 = *(const f32x4*)&G[ri];
    f32x4 g1 = *(const f32x4*)&G[ri + 4];
    #pragma unroll
    for (int j = 0; j < 8; ++j) {
      float xv = bf2f(xc[j]) * nfl0 * nws[oct * 8 + j];
      float sig = __builtin_amdgcn_rcpf(1.f + __builtin_amdgcn_exp2f(-acc[j] * L2E));
      float gg = (j < 4) ? g0[j] : g1[j - 4];
      tile[oct * 8 + j][li] = gg + xv * sig;
    }
  }
  __syncthreads();
  {
    const int lw = tid & 31, cr = tid >> 5;
    const float rsv = rs[0];
    for (int p = 0; p < 8; ++p) {
      int c = c0 + p * 8 + cr;
      size_t o = ((size_t)(b * 384 + c) << 10) + l0 + lw;
      out[o] = x[o] + rsv * tile[p * 8 + cr][lw];
    }
  }
}

// ---------------- host ----------------------------------------------------
extern "C" void kernel_launch(void* const* d_in, const int* in_sizes, int n_in,
                              void* d_out, int out_size, void* d_ws, size_t ws_size,
                              hipStream_t stream) {
  const float* x         = (const float*)d_in[0];
  const float* norm_w    = (const float*)d_in[1];
  const float* in_proj_w = (const float*)d_in[2];
  const float* conv1d_w  = (const float*)d_in[3];
  const float* conv1d_b  = (const float*)d_in[4];
  const float* x_proj_w  = (const float*)d_in[5];
  const float* dt_proj_w = (const float*)d_in[6];
  const float* dt_proj_b = (const float*)d_in[7];
  const float* A_log     = (const float*)d_in[8];
  const float* D_param   = (const float*)d_in[9];
  const float* out_proj_w= (const float*)d_in[10];
  const float* scale_mod = (const float*)d_in[11];
  const float* dw_w      = (const float*)d_in[12];
  const float* dw_b      = (const float*)d_in[13];
  const float* res_scale = (const float*)d_in[14];
  float* out = (float*)d_out;

  char* base = (char*)d_ws;
  size_t off = 0;
  auto alloc = [&](size_t bytes) {
    off = (off + 255) & ~(size_t)255;
    void* p = base + off;
    off += bytes;
    return p;
  };
  const size_t B_BLC = (size_t)8192 * 384 * 2;

  unsigned short* xb   = (unsigned short*)alloc(B_BLC);
  float*          nf   = (float*)alloc((size_t)8192 * 4);
  unsigned short* xz   = (unsigned short*)alloc((size_t)8192 * 768 * 2);
  unsigned short* u_b0 = (unsigned short*)alloc(B_BLC);
  unsigned short* u_b1 = (unsigned short*)alloc(B_BLC);
  unsigned short* dtp0 = (unsigned short*)alloc((size_t)8192 * 32 * 2);
  unsigned short* dtp1 = (unsigned short*)alloc((size_t)8192 * 32 * 2);
  float*          bc0  = (float*)alloc((size_t)8192 * 32 * 4);
  float*          bc1  = (float*)alloc((size_t)8192 * 32 * 4);
  unsigned short* de0  = (unsigned short*)alloc(B_BLC);
  unsigned short* de1  = (unsigned short*)alloc(B_BLC);
  unsigned short* Sb0  = (unsigned short*)alloc(B_BLC);
  unsigned short* Sb1  = (unsigned short*)alloc(B_BLC);
  float*          PH   = (float*)alloc((size_t)1572864 * 2 * 4);
  unsigned short* W_in = (unsigned short*)alloc((size_t)768 * 384 * 2);
  unsigned short* W_x  = (unsigned short*)alloc((size_t)64 * 384 * 2);
  unsigned short* W_dt = (unsigned short*)alloc((size_t)384 * 32 * 2);
  unsigned short* W_out= (unsigned short*)alloc((size_t)384 * 384 * 2);
  float*          A2   = (float*)alloc((size_t)384 * 16 * 4);
  float*          G    = (float*)alloc((size_t)8192 * 384 * 4);

  prep_k<<<dim3(1152, 5), 256, 0, stream>>>(in_proj_w, x_proj_w, dt_proj_w,
                                            out_proj_w, A_log, norm_w,
                                            W_in, W_x, W_dt, W_out, A2);
  transpose_k<<<dim3(32, 8), 256, 0, stream>>>(x, xb, nf);
  gemm128_k<0, 0><<<dim3(6, 64), 256, 0, stream>>>(xb, xb, W_in, 384, 768,
                                                   nullptr, xz, nf);
  conv_silu_k<<<dim3(128, 8, 2), 384, 0, stream>>>(xz, conv1d_w, conv1d_b,
                                                   u_b0, u_b1);
  gemm_k<1><<<dim3(1, 128, 2), 256, 0, stream>>>(u_b0, u_b1, W_x, 384, 64,
                                                 bc0, bc1, dtp0, dtp1, nullptr);
  gemm_k<2><<<dim3(6, 128, 2), 256, 0, stream>>>(dtp0, dtp1, W_dt, 32, 384,
                                                 nullptr, nullptr, de0, de1,
                                                 dt_proj_b);
  scan1_k<<<dim3(12, 8, 32), 512, 0, stream>>>(de0, de1, u_b0, u_b1, bc0, bc1,
                                               A2, PH);
  scan2_k<<<dim3(12, 8, 32), 512, 0, stream>>>(de0, de1, u_b0, u_b1, bc0, bc1,
                                               xz, A2, D_param, PH, Sb0, Sb1);
  gemm128_k<3, 1><<<dim3(3, 64), 256, 0, stream>>>(Sb0, Sb1, W_out, 384, 384,
                                                   G, nullptr, scale_mod);
  final_k<<<dim3(32, 6, 8), 256, 0, stream>>>(G, xb, nf, norm_w, x, dw_w, dw_b,
                                              res_scale, out);
}